// Round 13
// baseline (611.978 us; speedup 1.0000x reference)
//
#include <hip/hip_runtime.h>

#define T_SEQ 2048
#define C_DIM 1024
#define H_N   16
#define HS_D  64
#define V_DIM 32000

typedef float f32x4 __attribute__((ext_vector_type(4)));
typedef __bf16 bf16x8 __attribute__((ext_vector_type(8)));
typedef unsigned short us4 __attribute__((ext_vector_type(4)));
typedef unsigned short us8 __attribute__((ext_vector_type(8)));

__device__ inline unsigned short f2bf(float f) {
  unsigned int u = __float_as_uint(f);
  u = (u + 0x7FFFu + ((u >> 16) & 1u)) >> 16;
  return (unsigned short)u;
}

// ---------------- embed: h = tok_emb[x] + pos_emb, cast to bf16 ----------------
__global__ __launch_bounds__(256) void embed_kernel(
    const int* __restrict__ x, const float* __restrict__ tok,
    const float* __restrict__ pos, unsigned short* __restrict__ h) {
  int idx = blockIdx.x * 256 + threadIdx.x;   // over (B*T*C)/4
  int bt = idx >> 8;                          // 256 float4 per row
  int c4 = (idx & 255) * 4;
  int t = bt & (T_SEQ - 1);
  int tokid = x[bt];
  f32x4 a = *(const f32x4*)(tok + (size_t)tokid * C_DIM + c4);
  f32x4 b = *(const f32x4*)(pos + (size_t)t * C_DIM + c4);
  f32x4 s = a + b;
  us4 o;
  o[0] = f2bf(s[0]); o[1] = f2bf(s[1]); o[2] = f2bf(s[2]); o[3] = f2bf(s[3]);
  *(us4*)(h + (size_t)bt * C_DIM + c4) = o;
}

// ------------- repack wq/wk/wv [H,C,HS] f32 -> bf16 [3072][1024] (N,K) -------------
__global__ __launch_bounds__(256) void repack_qkv(
    const float* __restrict__ wq, const float* __restrict__ wk, const float* __restrict__ wv,
    const float* __restrict__ bq, const float* __restrict__ bk, const float* __restrict__ bv,
    unsigned short* __restrict__ wt, float* __restrict__ biasp) {
  int which = blockIdx.y;
  const float* w = (which == 0) ? wq : (which == 1) ? wk : wv;
  int i = blockIdx.x * 256 + threadIdx.x;   // 0 .. H*C*HS (=1M)
  int d = i & 63;
  int c = (i >> 6) & (C_DIM - 1);
  int hh = i >> 16;
  int n = which * 1024 + hh * 64 + d;
  wt[(size_t)n * C_DIM + c] = f2bf(w[i]);
  if (c == 0) {
    const float* bb = (which == 0) ? bq : (which == 1) ? bk : bv;
    biasp[n] = bb[hh * 64 + d];
  }
}

// ------------- transpose-repack w_head [C,V] f32 -> bf16 [V][C] -------------
__global__ __launch_bounds__(256) void repack_whead(
    const float* __restrict__ wh, unsigned short* __restrict__ wht) {
  __shared__ float tile[64][65];
  int v0 = blockIdx.x * 64;
  int c0 = blockIdx.y * 64;
  int tr = threadIdx.x >> 6;      // 0..3
  int tc = threadIdx.x & 63;
#pragma unroll
  for (int i = 0; i < 16; ++i) {
    int r = i * 4 + tr;
    tile[r][tc] = wh[(size_t)(c0 + r) * V_DIM + v0 + tc];
  }
  __syncthreads();
#pragma unroll
  for (int i = 0; i < 16; ++i) {
    int vr = i * 4 + tr;
    wht[(size_t)(v0 + vr) * C_DIM + c0 + tc] = f2bf(tile[tc][vr]);
  }
}

// ------------- 128x128 4-wave GEMM (m97 structure) + XCD swizzle, bf16 out (QKV) -------------
__global__ __launch_bounds__(256) void gemm_bf16_o16(
    const unsigned short* __restrict__ A, const unsigned short* __restrict__ Bt,
    const float* __restrict__ bias, unsigned short* __restrict__ Cout, int N, int Mtiles) {
  const int K = 1024;
  __shared__ unsigned short As[128 * 32];
  __shared__ unsigned short Bs[128 * 32];
  int tid = threadIdx.x;
  int lane = tid & 63, wvi = tid >> 6;
  int cpx = gridDim.x >> 3;
  int lin = blockIdx.x;
  int wg = (lin & 7) * cpx + (lin >> 3);
  int m0 = (wg % Mtiles) * 128;
  int n0 = (wg / Mtiles) * 128;
  int wmm = (wvi >> 1) * 64, wnn = (wvi & 1) * 64;
  int r16 = lane & 15, gg = lane >> 4;
  f32x4 acc[4][4] = {};

  for (int k0 = 0; k0 < K; k0 += 32) {
#pragma unroll
    for (int it = 0; it < 2; ++it) {
      int ch = it * 256 + wvi * 64 + lane;
      int row = ch >> 2, cc = (ch & 3) * 8;
      const unsigned short* ga = A + (size_t)(m0 + row) * K + k0 + cc;
      __builtin_amdgcn_global_load_lds(
          (const __attribute__((address_space(1))) void*)ga,
          (__attribute__((address_space(3))) void*)&As[ch * 8], 16, 0, 0);
      const unsigned short* gb = Bt + (size_t)(n0 + row) * K + k0 + cc;
      __builtin_amdgcn_global_load_lds(
          (const __attribute__((address_space(1))) void*)gb,
          (__attribute__((address_space(3))) void*)&Bs[ch * 8], 16, 0, 0);
    }
    __syncthreads();
    bf16x8 fa[4], fb[4];
#pragma unroll
    for (int m = 0; m < 4; ++m)
      fa[m] = *(const bf16x8*)&As[(wmm + m * 16 + r16) * 32 + gg * 8];
#pragma unroll
    for (int n = 0; n < 4; ++n)
      fb[n] = *(const bf16x8*)&Bs[(wnn + n * 16 + r16) * 32 + gg * 8];
#pragma unroll
    for (int m = 0; m < 4; ++m)
#pragma unroll
      for (int n = 0; n < 4; ++n)
        acc[m][n] = __builtin_amdgcn_mfma_f32_16x16x32_bf16(fa[m], fb[n], acc[m][n], 0, 0, 0);
    __syncthreads();
  }
#pragma unroll
  for (int m = 0; m < 4; ++m) {
    int row = m0 + wmm + m * 16 + gg * 4;
#pragma unroll
    for (int n = 0; n < 4; ++n) {
      int col = n0 + wnn + n * 16 + r16;
      float bval = bias[col];
#pragma unroll
      for (int j = 0; j < 4; ++j)
        Cout[(size_t)(row + j) * N + col] = f2bf(acc[m][n][j] + bval);
    }
  }
}

// ------------- transpose V: qkv_bf [B*T][3072] (cols 2048..3071) -> vt [B*H][64][T] -------------
__global__ __launch_bounds__(256) void transpose_v(
    const unsigned short* __restrict__ qkv, unsigned short* __restrict__ vt) {
  __shared__ unsigned short tile[64][72];
  int bh = blockIdx.y;
  int b = bh >> 4, h = bh & 15;
  int tb = blockIdx.x;
  int r = threadIdx.x >> 2;          // 0..63
  int c0 = (threadIdx.x & 3) * 16;
  const unsigned short* src = qkv + ((size_t)(b * T_SEQ) + tb * 64 + r) * 3072 + 2048 + h * 64 + c0;
  *(us8*)&tile[r][c0] = *(const us8*)src;
  *(us8*)&tile[r][c0 + 8] = *(const us8*)(src + 8);
  __syncthreads();
  unsigned short* dst = vt + (size_t)bh * 64 * T_SEQ + (size_t)r * T_SEQ + tb * 64 + c0;
  us8 o1, o2;
#pragma unroll
  for (int i = 0; i < 8; ++i) { o1[i] = tile[c0 + i][r]; o2[i] = tile[c0 + 8 + i][r]; }
  *(us8*)dst = o1;
  *(us8*)(dst + 8) = o2;
}

// ------------- 256x256 8-phase double-buffered GEMM (m201 template port) -------------
// 8 waves (2M x 4N), BK=64, 2 K-tiles per iteration, 8 phases/iter, 16 MFMA/phase.
// Phase: {ds-reads for quadrant; stage 1 half-tile (2 gload_lds); [lgkmcnt(8) if
// 12 reads]; barrier; lgkmcnt(0); sched_barrier; setprio(1) 16 MFMA setprio(0);
// [vmcnt(4) at P4/P8]; barrier}.  Quadrants per K-tile: Q(0,0) Q(0,1) Q(1,1) Q(1,0);
// B frags (ni 0..3) held in regs across the K-tile, A half reloaded at Q(1,1).
// Region lifetimes (derived): A(u) dead after P3 close, B(u) after P2 close,
// A(u+1) after P7, B(u+1) after P6. Stage plan (each target provably dead):
//   P1: Ah0(u+1)->As[1]  P2: Ah1(u+1)  P3: Bh0(u+2)->Bs[0]  P4: Bh1(u+2)
//   P5: Ah0(u+2)->As[0]  P6: Ah1(u+2)  P7: Bh0(u+3)->Bs[1]  P8: Bh1(u+3)
// FIFO vmcnt: at P4-end allow B(u+2)'s 4 loads -> vmcnt(4); at P8-end allow
// B(u+3)'s 4 -> vmcnt(4). Tail it=7: vmcnt(0) at P4. Never drains mid-loop else.
// MFMA operands swapped (mfma(B,A)): acc[mf][ni][j] = C[mf*16+l16][ni*16+g*4+j]
// -> coalesced f32x4 NORMAL stores (nt reverted: R9/R11/R12 all showed RMW/bloat).
#define GK 1024
#define GNT 16   // K / 64

__global__ __launch_bounds__(512, 1) void gemm256(
    const unsigned short* __restrict__ A, const unsigned short* __restrict__ Bt,
    const float* __restrict__ bias, float* __restrict__ Cout, int N, int Mtiles) {
  __shared__ unsigned short As[2][256 * 64];
  __shared__ unsigned short Bs[2][256 * 64];
  int tid = threadIdx.x;
  int lane = tid & 63;
  int wid = tid >> 6;
  int wm = wid >> 2, wn = wid & 3;
  int l16 = lane & 15, g = lane >> 4;
  int swz = l16 & 7;

  int cpx = gridDim.x >> 3;
  int lin = blockIdx.x;
  int wg = (lin & 7) * cpx + (lin >> 3);
  int m0 = (wg % Mtiles) * 256;
  int n0 = (wg / Mtiles) * 256;

  // stage one 128-row half of a 256x64 K-tile: 2 gload_lds / thread
  auto stageH = [&](const unsigned short* __restrict__ G, int base,
                    unsigned short* lds, int kt, int h) {
#pragma unroll
    for (int q = 0; q < 2; ++q) {
      int chunk = q * 512 + tid;
      int rowl = chunk >> 3;
      int row = h * 128 + rowl;
      int cpos = chunk & 7;
      int c = cpos ^ (row & 7);           // inverse swizzle on global source
      const unsigned short* src = G + (size_t)(base + row) * GK + kt * 64 + c * 8;
      __builtin_amdgcn_global_load_lds(
          (const __attribute__((address_space(1))) void*)src,
          (__attribute__((address_space(3))) void*)(lds + row * 64 + cpos * 8), 16, 0, 0);
    }
  };

  // prologue: 12 loads in steady-state FIFO order (virtual prev-iter P3..P8)
  stageH(Bt, n0, Bs[0], 0, 0); stageH(Bt, n0, Bs[0], 0, 1);
  stageH(A,  m0, As[0], 0, 0); stageH(A,  m0, As[0], 0, 1);
  stageH(Bt, n0, Bs[1], 1, 0); stageH(Bt, n0, Bs[1], 1, 1);
  asm volatile("s_waitcnt vmcnt(4)" ::: "memory");   // A(0),B(0) landed; B(1) in flight
  asm volatile("s_barrier" ::: "memory");

  f32x4 acc[8][4] = {};
  bf16x8 bA[4][2], bB[4][2];

  auto readA = [&](const char* Ab, int mh) {
#pragma unroll
    for (int mi = 0; mi < 4; ++mi) {
      int row = wm * 128 + mh * 64 + mi * 16 + l16;
#pragma unroll
      for (int kk = 0; kk < 2; ++kk)
        bA[mi][kk] = *(const bf16x8*)(Ab + row * 128 + (((kk * 4 + g) ^ swz) * 16));
    }
  };
  auto readB2 = [&](const char* Bb, int nh) {
#pragma unroll
    for (int ni = 0; ni < 2; ++ni) {
      int row = wn * 64 + nh * 32 + ni * 16 + l16;
#pragma unroll
      for (int kk = 0; kk < 2; ++kk)
        bB[nh * 2 + ni][kk] = *(const bf16x8*)(Bb + row * 128 + (((kk * 4 + g) ^ swz) * 16));
    }
  };
  auto mfma16 = [&](int a, int b) {  // quadrant (a = m-half, b = n-half)
#pragma unroll
    for (int mi = 0; mi < 4; ++mi)
#pragma unroll
      for (int ni = 0; ni < 2; ++ni)
#pragma unroll
        for (int kk = 0; kk < 2; ++kk)
          acc[4 * a + mi][2 * b + ni] = __builtin_amdgcn_mfma_f32_16x16x32_bf16(
              bB[2 * b + ni][kk], bA[mi][kk], acc[4 * a + mi][2 * b + ni], 0, 0, 0);
  };

  for (int it = 0; it < 8; ++it) {
    int u = 2 * it;                    // K-tiles u (bufs[0]), u+1 (bufs[1])
    bool pf = (it < 7);
    const char* A0 = (const char*)As[0];
    const char* B0 = (const char*)Bs[0];
    const char* A1 = (const char*)As[1];
    const char* B1 = (const char*)Bs[1];

    // ---- P1: tile u, Q(0,0); 12 reads; stage Ah0(u+1) ----
    readA(A0, 0); readB2(B0, 0);
    stageH(A, m0, As[1], u + 1, 0);
    asm volatile("s_waitcnt lgkmcnt(8)" ::: "memory");
    asm volatile("s_barrier" ::: "memory");
    asm volatile("s_waitcnt lgkmcnt(0)" ::: "memory");
    __builtin_amdgcn_sched_barrier(0);
    __builtin_amdgcn_s_setprio(1); mfma16(0, 0); __builtin_amdgcn_s_setprio(0);
    asm volatile("s_barrier" ::: "memory");

    // ---- P2: Q(0,1); 4 reads; stage Ah1(u+1) ----
    readB2(B0, 1);
    stageH(A, m0, As[1], u + 1, 1);
    asm volatile("s_barrier" ::: "memory");
    asm volatile("s_waitcnt lgkmcnt(0)" ::: "memory");
    __builtin_amdgcn_sched_barrier(0);
    __builtin_amdgcn_s_setprio(1); mfma16(0, 1); __builtin_amdgcn_s_setprio(0);
    asm volatile("s_barrier" ::: "memory");

    // ---- P3: Q(1,1); 8 reads; stage Bh0(u+2) ----
    readA(A0, 1);
    if (pf) stageH(Bt, n0, Bs[0], u + 2, 0);
    asm volatile("s_barrier" ::: "memory");
    asm volatile("s_waitcnt lgkmcnt(0)" ::: "memory");
    __builtin_amdgcn_sched_barrier(0);
    __builtin_amdgcn_s_setprio(1); mfma16(1, 1); __builtin_amdgcn_s_setprio(0);
    asm volatile("s_barrier" ::: "memory");

    // ---- P4: Q(1,0); 0 reads; stage Bh1(u+2); vmcnt checkpoint ----
    if (pf) stageH(Bt, n0, Bs[0], u + 2, 1);
    asm volatile("s_barrier" ::: "memory");
    __builtin_amdgcn_s_setprio(1); mfma16(1, 0); __builtin_amdgcn_s_setprio(0);
    if (pf) asm volatile("s_waitcnt vmcnt(4)" ::: "memory");
    else    asm volatile("s_waitcnt vmcnt(0)" ::: "memory");
    asm volatile("s_barrier" ::: "memory");

    // ---- P5: tile u+1, Q(0,0); 12 reads; stage Ah0(u+2) ----
    readA(A1, 0); readB2(B1, 0);
    if (pf) stageH(A, m0, As[0], u + 2, 0);
    asm volatile("s_waitcnt lgkmcnt(8)" ::: "memory");
    asm volatile("s_barrier" ::: "memory");
    asm volatile("s_waitcnt lgkmcnt(0)" ::: "memory");
    __builtin_amdgcn_sched_barrier(0);
    __builtin_amdgcn_s_setprio(1); mfma16(0, 0); __builtin_amdgcn_s_setprio(0);
    asm volatile("s_barrier" ::: "memory");

    // ---- P6: Q(0,1); 4 reads; stage Ah1(u+2) ----
    readB2(B1, 1);
    if (pf) stageH(A, m0, As[0], u + 2, 1);
    asm volatile("s_barrier" ::: "memory");
    asm volatile("s_waitcnt lgkmcnt(0)" ::: "memory");
    __builtin_amdgcn_sched_barrier(0);
    __builtin_amdgcn_s_setprio(1); mfma16(0, 1); __builtin_amdgcn_s_setprio(0);
    asm volatile("s_barrier" ::: "memory");

    // ---- P7: Q(1,1); 8 reads; stage Bh0(u+3) ----
    readA(A1, 1);
    if (pf) stageH(Bt, n0, Bs[1], u + 3, 0);
    asm volatile("s_barrier" ::: "memory");
    asm volatile("s_waitcnt lgkmcnt(0)" ::: "memory");
    __builtin_amdgcn_sched_barrier(0);
    __builtin_amdgcn_s_setprio(1); mfma16(1, 1); __builtin_amdgcn_s_setprio(0);
    asm volatile("s_barrier" ::: "memory");

    // ---- P8: Q(1,0); 0 reads; stage Bh1(u+3); vmcnt checkpoint ----
    if (pf) stageH(Bt, n0, Bs[1], u + 3, 1);
    asm volatile("s_barrier" ::: "memory");
    __builtin_amdgcn_s_setprio(1); mfma16(1, 0); __builtin_amdgcn_s_setprio(0);
    if (pf) asm volatile("s_waitcnt vmcnt(4)" ::: "memory");
    asm volatile("s_barrier" ::: "memory");
  }

  // ---- epilogue: swapped-layout fragments -> coalesced f32x4 normal stores ----
#pragma unroll
  for (int mf = 0; mf < 8; ++mf) {
    int row = m0 + wm * 128 + mf * 16 + l16;
    float* outp = Cout + (size_t)row * N + n0 + wn * 64;
#pragma unroll
    for (int ni = 0; ni < 4; ++ni) {
      f32x4 v = acc[mf][ni];
      f32x4 bv = *(const f32x4*)&bias[n0 + wn * 64 + ni * 16 + g * 4];
      v += bv;
      *(f32x4*)(outp + ni * 16 + g * 4) = v;
    }
  }
}

// ------------- MFMA flash attention, bf16 in, DMA-staged, double-buffered -------------
__global__ __launch_bounds__(256) void attn_mfma(
    const unsigned short* __restrict__ qkv, const unsigned short* __restrict__ vt,
    unsigned short* __restrict__ y) {
  __shared__ unsigned short Kl[2][4096];
  __shared__ unsigned short Vl[2][4096];
  __shared__ char Pl[8192];

  int bh = blockIdx.y;
  int b = bh >> 4, h = bh & 15;
  int qb = (T_SEQ / 64 - 1) - blockIdx.x;
  int tid = threadIdx.x;
  int lane = tid & 63, w = tid >> 6;
  int l16 = lane & 15, g = lane >> 4;
  size_t bT = (size_t)b * T_SEQ;
  const float scale2 = 0.03125f * 1.44269504f;  // C^-0.5 * log2(e)

  const unsigned short* qrow = qkv + (bT + qb * 64 + w * 16 + l16) * 3072 + h * 64;
  bf16x8 qf[2] = { *(const bf16x8*)(qrow + g * 8), *(const bf16x8*)(qrow + 32 + g * 8) };

  f32x4 yacc[4] = {};
  float mrun[4], lrun[4];
#pragma unroll
  for (int j = 0; j < 4; ++j) { mrun[j] = -3.0e38f; lrun[j] = 0.f; }

  auto stageK = [&](int kb, int buf) {
    const unsigned short* base = qkv + (bT + kb * 64) * 3072 + 1024 + h * 64;
#pragma unroll
    for (int q2 = 0; q2 < 2; ++q2) {
      int chunk = q2 * 256 + tid;
      int row = chunk >> 3, cpos = chunk & 7;
      int c = cpos ^ (row & 7);
      const unsigned short* src = base + (size_t)row * 3072 + c * 8;
      __builtin_amdgcn_global_load_lds(
          (const __attribute__((address_space(1))) void*)src,
          (__attribute__((address_space(3))) void*)&Kl[buf][chunk * 8], 16, 0, 0);
    }
  };
  auto stageV = [&](int kb, int buf) {
    const unsigned short* base = vt + (size_t)bh * 64 * T_SEQ + kb * 64;
#pragma unroll
    for (int q2 = 0; q2 < 2; ++q2) {
      int chunk = q2 * 256 + tid;
      int row = chunk >> 3, cpos = chunk & 7;
      int c = cpos ^ (row & 7);
      const unsigned short* src = base + (size_t)row * T_SEQ + c * 8;
      __builtin_amdgcn_global_load_lds(
          (const __attribute__((address_space(1))) void*)src,
          (__attribute__((address_space(3))) void*)&Vl[buf][chunk * 8], 16, 0, 0);
    }
  };

  stageK(0, 0); stageV(0, 0);

  for (int kb = 0; kb <= qb; ++kb) {
    int buf = kb & 1;
    if (kb < qb) { stageK(kb + 1, buf ^ 1); stageV(kb + 1, buf ^ 1); }
    if (kb < qb) asm volatile("s_waitcnt vmcnt(4)" ::: "memory");
    else         asm volatile("s_waitcnt vmcnt(0)" ::: "memory");
    asm volatile("s_barrier" ::: "memory");

    // ---- S = Q K^T ----
    f32x4 s[4] = {};
#pragma unroll
    for (int kk = 0; kk < 2; ++kk)
#pragma unroll
      for (int n = 0; n < 4; ++n) {
        int krow = n * 16 + l16;
        bf16x8 fb = *(const bf16x8*)((const char*)Kl[buf] + krow * 128 + (((kk * 4 + g) ^ (krow & 7)) * 16));
        s[n] = __builtin_amdgcn_mfma_f32_16x16x32_bf16(qf[kk], fb, s[n], 0, 0, 0);
      }

    // ---- online softmax (log2 domain) ----
    bool diag = (kb == qb);
    float pr[4][4];
    float corr[4];
#pragma unroll
    for (int j = 0; j < 4; ++j) {
      int rloc = w * 16 + g * 4 + j;
      float m = -3.0e38f;
#pragma unroll
      for (int n = 0; n < 4; ++n) {
        float v = s[n][j] * scale2;
        if (diag && (n * 16 + l16) > rloc) v = -3.0e38f;
        pr[n][j] = v;
        m = fmaxf(m, v);
      }
      m = fmaxf(m, __shfl_xor(m, 1));
      m = fmaxf(m, __shfl_xor(m, 2));
      m = fmaxf(m, __shfl_xor(m, 4));
      m = fmaxf(m, __shfl_xor(m, 8));
      float mn = fmaxf(mrun[j], m);
      corr[j] = exp2f(mrun[j] - mn);
      mrun[j] = mn;
      float ps = 0.f;
#pragma unroll
      for (int n = 0; n < 4; ++n) {
        float e = exp2f(pr[n][j] - mn);
        pr[n][j] = e;
        ps += e;
      }
      ps += __shfl_xor(ps, 1);
      ps += __shfl_xor(ps, 2);
      ps += __shfl_xor(ps, 4);
      ps += __shfl_xor(ps, 8);
      lrun[j] = lrun[j] * corr[j] + ps;
    }
#pragma unroll
    for (int n = 0; n < 4; ++n)
#pragma unroll
      for (int j = 0; j < 4; ++j)
        yacc[n][j] *= corr[j];

    // ---- P strip (wave-private rows) ----
#pragma unroll
    for (int j = 0; j < 4; ++j) {
      int row = w * 16 + g * 4 + j;
#pragma unroll
      for (int n = 0; n < 4; ++n)
        *(unsigned short*)(Pl + ((row * 128 + (n * 16 + l16) * 2) ^ ((row & 7) << 4))) = f2bf(pr[n][j]);
    }

    // ---- y += P V ----
#pragma unroll
    for (int kk = 0; kk < 2; ++kk) {
      int prow = w * 16 + l16;
      bf16x8 fa = *(const bf16x8*)(Pl + ((prow * 128 + (kk * 32 + g * 8) * 2) ^ ((prow & 7) << 4)));
#pragma unroll
      for (int n = 0; n < 4; ++n) {
        int vrow = n * 16 + l16;
        bf16x8 fbv = *(const bf16x8*)((const char*)Vl[buf] + vrow * 128 + (((kk * 4 + g) ^ (vrow & 7)) * 16));
        yacc[n] = __builtin_amdgcn_mfma_f32_16x16x32_bf16(fa, fbv, yacc[n], 0, 0, 0);
      }
    }
    asm volatile("s_barrier" ::: "memory");
  }

  // ---- output ----
#pragma unroll
  for (int j = 0; j < 4; ++j) {
    float inv = 1.0f / lrun[j];
    int row = qb * 64 + w * 16 + g * 4 + j;
    unsigned short* yo = y + (bT + row) * C_DIM + h * 64;
#pragma unroll
    for (int n = 0; n < 4; ++n)
      yo[n * 16 + l16] = f2bf(yacc[n][j] * inv);
  }
}

extern "C" void kernel_launch(void* const* d_in, const int* in_sizes, int n_in,
                              void* d_out, int out_size, void* d_ws, size_t ws_size,
                              hipStream_t stream) {
  const int*   x    = (const int*)d_in[0];
  const float* tok  = (const float*)d_in[1];
  const float* pos  = (const float*)d_in[2];
  const float* wq   = (const float*)d_in[3];
  const float* bq   = (const float*)d_in[4];
  const float* wk   = (const float*)d_in[5];
  const float* bk   = (const float*)d_in[6];
  const float* wv   = (const float*)d_in[7];
  const float* bv   = (const float*)d_in[8];
  const float* wh   = (const float*)d_in[9];
  const float* bhd  = (const float*)d_in[10];
  float* out = (float*)d_out;

  char* ws = (char*)d_ws;
  size_t off = 0;
  auto alloc = [&](size_t bytes) {
    void* p = ws + off;
    off += (bytes + 255) & ~(size_t)255;
    return p;
  };
  unsigned short* h_bf    = (unsigned short*)alloc((size_t)4096 * 1024 * 2);
  unsigned short* wqkv_t  = (unsigned short*)alloc((size_t)3072 * 1024 * 2);
  float*          qbias   = (float*)alloc((size_t)3072 * 4);
  unsigned short* wh_t    = (unsigned short*)alloc((size_t)V_DIM * 1024 * 2);
  unsigned short* qkv_bf  = (unsigned short*)alloc((size_t)4096 * 3072 * 2);
  unsigned short* vtb     = (unsigned short*)alloc((size_t)32 * 64 * T_SEQ * 2);
  unsigned short* ybf     = (unsigned short*)alloc((size_t)4096 * 1024 * 2);

  embed_kernel<<<4096, 256, 0, stream>>>(x, tok, pos, h_bf);
  repack_qkv<<<dim3(4096, 3), 256, 0, stream>>>(wq, wk, wv, bq, bk, bv, wqkv_t, qbias);
  repack_whead<<<dim3(V_DIM / 64, 16), 256, 0, stream>>>(wh, wh_t);
  // QKV proj (bf16 out): M=4096 (32 m-tiles, fastest), N=3072 -> 768 blocks
  gemm_bf16_o16<<<768, 256, 0, stream>>>(h_bf, wqkv_t, qbias, qkv_bf, 3072, 32);
  transpose_v<<<dim3(T_SEQ / 64, 2 * H_N), 256, 0, stream>>>(qkv_bf, vtb);
  attn_mfma<<<dim3(T_SEQ / 64, 2 * H_N), 256, 0, stream>>>(qkv_bf, vtb, ybf);
  // head: M=4096, N=32000 -> 16 x 125 = 2000 blocks (%8==0)
  gemm256<<<2000, 512, 0, stream>>>(ybf, wh_t, bhd, out, V_DIM, 16);
}

// Round 14
// 604.167 us; speedup vs baseline: 1.0129x; 1.0129x over previous
//
#include <hip/hip_runtime.h>

#define T_SEQ 2048
#define C_DIM 1024
#define H_N   16
#define HS_D  64
#define V_DIM 32000

typedef float f32x4 __attribute__((ext_vector_type(4)));
typedef __bf16 bf16x8 __attribute__((ext_vector_type(8)));
typedef unsigned short us4 __attribute__((ext_vector_type(4)));
typedef unsigned short us8 __attribute__((ext_vector_type(8)));

__device__ inline unsigned short f2bf(float f) {
  unsigned int u = __float_as_uint(f);
  u = (u + 0x7FFFu + ((u >> 16) & 1u)) >> 16;
  return (unsigned short)u;
}

// ---------------- embed: h = tok_emb[x] + pos_emb, cast to bf16 ----------------
__global__ __launch_bounds__(256) void embed_kernel(
    const int* __restrict__ x, const float* __restrict__ tok,
    const float* __restrict__ pos, unsigned short* __restrict__ h) {
  int idx = blockIdx.x * 256 + threadIdx.x;   // over (B*T*C)/4
  int bt = idx >> 8;                          // 256 float4 per row
  int c4 = (idx & 255) * 4;
  int t = bt & (T_SEQ - 1);
  int tokid = x[bt];
  f32x4 a = *(const f32x4*)(tok + (size_t)tokid * C_DIM + c4);
  f32x4 b = *(const f32x4*)(pos + (size_t)t * C_DIM + c4);
  f32x4 s = a + b;
  us4 o;
  o[0] = f2bf(s[0]); o[1] = f2bf(s[1]); o[2] = f2bf(s[2]); o[3] = f2bf(s[3]);
  *(us4*)(h + (size_t)bt * C_DIM + c4) = o;
}

// ------------- repack wq/wk/wv [H,C,HS] f32 -> bf16 [3072][1024] (N,K) -------------
__global__ __launch_bounds__(256) void repack_qkv(
    const float* __restrict__ wq, const float* __restrict__ wk, const float* __restrict__ wv,
    const float* __restrict__ bq, const float* __restrict__ bk, const float* __restrict__ bv,
    unsigned short* __restrict__ wt, float* __restrict__ biasp) {
  int which = blockIdx.y;
  const float* w = (which == 0) ? wq : (which == 1) ? wk : wv;
  int i = blockIdx.x * 256 + threadIdx.x;   // 0 .. H*C*HS (=1M)
  int d = i & 63;
  int c = (i >> 6) & (C_DIM - 1);
  int hh = i >> 16;
  int n = which * 1024 + hh * 64 + d;
  wt[(size_t)n * C_DIM + c] = f2bf(w[i]);
  if (c == 0) {
    const float* bb = (which == 0) ? bq : (which == 1) ? bk : bv;
    biasp[n] = bb[hh * 64 + d];
  }
}

// ------------- transpose-repack w_head [C,V] f32 -> bf16 [V][C], vectorized -------------
__global__ __launch_bounds__(256) void repack_whead(
    const float* __restrict__ wh, unsigned short* __restrict__ wht) {
  __shared__ float tile[64][65];
  int v0 = blockIdx.x * 64;
  int c0 = blockIdx.y * 64;
  int tr = threadIdx.x >> 4;         // 0..15
  int tc = (threadIdx.x & 15) * 4;   // 0,4,..,60
#pragma unroll
  for (int i = 0; i < 4; ++i) {
    int r = i * 16 + tr;             // c-row
    *(f32x4*)&tile[r][tc] = *(const f32x4*)&wh[(size_t)(c0 + r) * V_DIM + v0 + tc];
  }
  __syncthreads();
#pragma unroll
  for (int i = 0; i < 4; ++i) {
    int vr = i * 16 + tr;            // v-row
    us4 o;
#pragma unroll
    for (int k = 0; k < 4; ++k) o[k] = f2bf(tile[tc + k][vr]);
    *(us4*)&wht[(size_t)(v0 + vr) * C_DIM + c0 + tc] = o;
  }
}

// ------------- 128x128 4-wave QKV GEMM, bf16 out, V-transpose fused -------------
// Q/K n-tiles (col<2048) -> qkv_bf rows; V n-tiles (col>=2048, uniform per block)
// -> vt[b*16+h][d][t] directly (us4 of 4 consecutive t). transpose_v eliminated.
__global__ __launch_bounds__(256) void gemm_bf16_o16(
    const unsigned short* __restrict__ A, const unsigned short* __restrict__ Bt,
    const float* __restrict__ bias, unsigned short* __restrict__ Cout,
    unsigned short* __restrict__ vt, int N, int Mtiles) {
  const int K = 1024;
  __shared__ unsigned short As[128 * 32];
  __shared__ unsigned short Bs[128 * 32];
  int tid = threadIdx.x;
  int lane = tid & 63, wvi = tid >> 6;
  int cpx = gridDim.x >> 3;
  int lin = blockIdx.x;
  int wg = (lin & 7) * cpx + (lin >> 3);
  int m0 = (wg % Mtiles) * 128;
  int n0 = (wg / Mtiles) * 128;
  int wmm = (wvi >> 1) * 64, wnn = (wvi & 1) * 64;
  int r16 = lane & 15, gg = lane >> 4;
  f32x4 acc[4][4] = {};

  for (int k0 = 0; k0 < K; k0 += 32) {
#pragma unroll
    for (int it = 0; it < 2; ++it) {
      int ch = it * 256 + wvi * 64 + lane;
      int row = ch >> 2, cc = (ch & 3) * 8;
      const unsigned short* ga = A + (size_t)(m0 + row) * K + k0 + cc;
      __builtin_amdgcn_global_load_lds(
          (const __attribute__((address_space(1))) void*)ga,
          (__attribute__((address_space(3))) void*)&As[ch * 8], 16, 0, 0);
      const unsigned short* gb = Bt + (size_t)(n0 + row) * K + k0 + cc;
      __builtin_amdgcn_global_load_lds(
          (const __attribute__((address_space(1))) void*)gb,
          (__attribute__((address_space(3))) void*)&Bs[ch * 8], 16, 0, 0);
    }
    __syncthreads();
    bf16x8 fa[4], fb[4];
#pragma unroll
    for (int m = 0; m < 4; ++m)
      fa[m] = *(const bf16x8*)&As[(wmm + m * 16 + r16) * 32 + gg * 8];
#pragma unroll
    for (int n = 0; n < 4; ++n)
      fb[n] = *(const bf16x8*)&Bs[(wnn + n * 16 + r16) * 32 + gg * 8];
#pragma unroll
    for (int m = 0; m < 4; ++m)
#pragma unroll
      for (int n = 0; n < 4; ++n)
        acc[m][n] = __builtin_amdgcn_mfma_f32_16x16x32_bf16(fa[m], fb[n], acc[m][n], 0, 0, 0);
    __syncthreads();
  }
#pragma unroll
  for (int m = 0; m < 4; ++m) {
    int row = m0 + wmm + m * 16 + gg * 4;
#pragma unroll
    for (int n = 0; n < 4; ++n) {
      int col = n0 + wnn + n * 16 + r16;
      float bval = bias[col];
      if (n0 < 2048) {   // Q/K tile (uniform branch; n0 multiple of 128)
#pragma unroll
        for (int j = 0; j < 4; ++j)
          Cout[(size_t)(row + j) * N + col] = f2bf(acc[m][n][j] + bval);
      } else {           // V tile -> transposed vt[b*16+h][d][t]
        int d = (col - 2048) & 63, hh = (col - 2048) >> 6;
        int b = row >> 11, t0 = row & 2047;
        us4 o;
#pragma unroll
        for (int j = 0; j < 4; ++j) o[j] = f2bf(acc[m][n][j] + bval);
        *(us4*)&vt[((size_t)(b * 16 + hh) * 64 + d) * T_SEQ + t0] = o;
      }
    }
  }
}

// ------------- 256x256 double-buffered 2-phase GEMM (R7 schedule, frozen) -------------
// Swapped MFMA operands (mfma(B,A)): acc[mf][ni] = C[mf-row][4 consecutive n-cols]
// -> coalesced f32x4 NORMAL stores (nt permanently reverted: RMW/bloat in R9/R11/R12).
#define GK 1024
#define GNT 16   // K / 64

__global__ __launch_bounds__(512, 1) void gemm256(
    const unsigned short* __restrict__ A, const unsigned short* __restrict__ Bt,
    const float* __restrict__ bias, float* __restrict__ Cout, int N, int Mtiles) {
  __shared__ unsigned short As[2][256 * 64];
  __shared__ unsigned short Bs[2][256 * 64];
  int tid = threadIdx.x;
  int lane = tid & 63;
  int wid = tid >> 6;
  int wm = wid >> 2, wn = wid & 3;
  int l16 = lane & 15, g = lane >> 4;
  int swz = l16 & 7;

  int cpx = gridDim.x >> 3;
  int lin = blockIdx.x;
  int wg = (lin & 7) * cpx + (lin >> 3);
  int m0 = (wg % Mtiles) * 256;
  int n0 = (wg / Mtiles) * 256;

  auto stageA2 = [&](int kt, int mh) {
    unsigned short* lds = As[kt & 1];
#pragma unroll
    for (int q = 0; q < 2; ++q) {
      int chunk = q * 512 + tid;
      int rr = chunk >> 3;
      int row = (rr & 63) + ((rr >> 6) << 7) + mh * 64;
      int cpos = chunk & 7;
      int c = cpos ^ (row & 7);
      const unsigned short* src = A + (size_t)(m0 + row) * GK + kt * 64 + c * 8;
      __builtin_amdgcn_global_load_lds(
          (const __attribute__((address_space(1))) void*)src,
          (__attribute__((address_space(3))) void*)(lds + row * 64 + cpos * 8), 16, 0, 0);
    }
  };
  auto stageB4 = [&](int kt) {
    unsigned short* lds = Bs[kt & 1];
#pragma unroll
    for (int q = 0; q < 4; ++q) {
      int chunk = q * 512 + tid;
      int row = chunk >> 3;
      int cpos = chunk & 7;
      int c = cpos ^ (row & 7);
      const unsigned short* src = Bt + (size_t)(n0 + row) * GK + kt * 64 + c * 8;
      __builtin_amdgcn_global_load_lds(
          (const __attribute__((address_space(1))) void*)src,
          (__attribute__((address_space(3))) void*)(lds + row * 64 + cpos * 8), 16, 0, 0);
    }
  };

  stageA2(0, 0); stageB4(0);
  stageA2(0, 1);
  stageA2(1, 0); stageB4(1);
  asm volatile("s_waitcnt vmcnt(8)" ::: "memory");
  asm volatile("s_barrier" ::: "memory");

  f32x4 acc[8][4] = {};

  for (int t = 0; t < GNT; ++t) {
    const char* Ab = (const char*)As[t & 1];
    const char* Bb = (const char*)Bs[t & 1];
    bf16x8 bA[4][2], bB[4][2];

#pragma unroll
    for (int mi = 0; mi < 4; ++mi) {
      int row = wm * 128 + mi * 16 + l16;
#pragma unroll
      for (int kk = 0; kk < 2; ++kk)
        bA[mi][kk] = *(const bf16x8*)(Ab + row * 128 + (((kk * 4 + g) ^ swz) * 16));
    }
#pragma unroll
    for (int ni = 0; ni < 4; ++ni) {
      int row = wn * 64 + ni * 16 + l16;
#pragma unroll
      for (int kk = 0; kk < 2; ++kk)
        bB[ni][kk] = *(const bf16x8*)(Bb + row * 128 + (((kk * 4 + g) ^ swz) * 16));
    }
    if (t + 1 < GNT) stageA2(t + 1, 1);
    asm volatile("s_barrier" ::: "memory");
    asm volatile("s_waitcnt lgkmcnt(0)" ::: "memory");
    __builtin_amdgcn_sched_barrier(0);
    __builtin_amdgcn_s_setprio(1);
#pragma unroll
    for (int mi = 0; mi < 4; ++mi)
#pragma unroll
      for (int ni = 0; ni < 4; ++ni)
#pragma unroll
        for (int kk = 0; kk < 2; ++kk)
          acc[mi][ni] = __builtin_amdgcn_mfma_f32_16x16x32_bf16(bB[ni][kk], bA[mi][kk], acc[mi][ni], 0, 0, 0);
    __builtin_amdgcn_s_setprio(0);
    if (t + 1 < GNT) asm volatile("s_waitcnt vmcnt(8)" ::: "memory");
    else             asm volatile("s_waitcnt vmcnt(0)" ::: "memory");
    asm volatile("s_barrier" ::: "memory");

#pragma unroll
    for (int mi = 0; mi < 4; ++mi) {
      int row = wm * 128 + 64 + mi * 16 + l16;
#pragma unroll
      for (int kk = 0; kk < 2; ++kk)
        bA[mi][kk] = *(const bf16x8*)(Ab + row * 128 + (((kk * 4 + g) ^ swz) * 16));
    }
    if (t + 2 < GNT) { stageA2(t + 2, 0); stageB4(t + 2); }
    asm volatile("s_barrier" ::: "memory");
    asm volatile("s_waitcnt lgkmcnt(0)" ::: "memory");
    __builtin_amdgcn_sched_barrier(0);
    __builtin_amdgcn_s_setprio(1);
#pragma unroll
    for (int mi = 0; mi < 4; ++mi)
#pragma unroll
      for (int ni = 0; ni < 4; ++ni)
#pragma unroll
        for (int kk = 0; kk < 2; ++kk)
          acc[4 + mi][ni] = __builtin_amdgcn_mfma_f32_16x16x32_bf16(bB[ni][kk], bA[mi][kk], acc[4 + mi][ni], 0, 0, 0);
    __builtin_amdgcn_s_setprio(0);
    if (t + 2 < GNT)       asm volatile("s_waitcnt vmcnt(8)" ::: "memory");
    else if (t + 2 == GNT) asm volatile("s_waitcnt vmcnt(2)" ::: "memory");
    asm volatile("s_barrier" ::: "memory");
  }

  // ---- epilogue: coalesced f32x4 normal stores ----
#pragma unroll
  for (int mf = 0; mf < 8; ++mf) {
    int row = m0 + wm * 128 + mf * 16 + l16;
    float* outp = Cout + (size_t)row * N + n0 + wn * 64;
#pragma unroll
    for (int ni = 0; ni < 4; ++ni) {
      f32x4 v = acc[mf][ni];
      f32x4 bv = *(const f32x4*)&bias[n0 + wn * 64 + ni * 16 + g * 4];
      v += bv;
      *(f32x4*)(outp + ni * 16 + g * 4) = v;
    }
  }
}

// ------------- MFMA flash attention, bf16 in, DMA-staged, double-buffered -------------
__global__ __launch_bounds__(256) void attn_mfma(
    const unsigned short* __restrict__ qkv, const unsigned short* __restrict__ vt,
    unsigned short* __restrict__ y) {
  __shared__ unsigned short Kl[2][4096];
  __shared__ unsigned short Vl[2][4096];
  __shared__ char Pl[8192];

  int bh = blockIdx.y;
  int b = bh >> 4, h = bh & 15;
  int qb = (T_SEQ / 64 - 1) - blockIdx.x;
  int tid = threadIdx.x;
  int lane = tid & 63, w = tid >> 6;
  int l16 = lane & 15, g = lane >> 4;
  size_t bT = (size_t)b * T_SEQ;
  const float scale2 = 0.03125f * 1.44269504f;  // C^-0.5 * log2(e)

  const unsigned short* qrow = qkv + (bT + qb * 64 + w * 16 + l16) * 3072 + h * 64;
  bf16x8 qf[2] = { *(const bf16x8*)(qrow + g * 8), *(const bf16x8*)(qrow + 32 + g * 8) };

  f32x4 yacc[4] = {};
  float mrun[4], lrun[4];
#pragma unroll
  for (int j = 0; j < 4; ++j) { mrun[j] = -3.0e38f; lrun[j] = 0.f; }

  auto stageK = [&](int kb, int buf) {
    const unsigned short* base = qkv + (bT + kb * 64) * 3072 + 1024 + h * 64;
#pragma unroll
    for (int q2 = 0; q2 < 2; ++q2) {
      int chunk = q2 * 256 + tid;
      int row = chunk >> 3, cpos = chunk & 7;
      int c = cpos ^ (row & 7);
      const unsigned short* src = base + (size_t)row * 3072 + c * 8;
      __builtin_amdgcn_global_load_lds(
          (const __attribute__((address_space(1))) void*)src,
          (__attribute__((address_space(3))) void*)&Kl[buf][chunk * 8], 16, 0, 0);
    }
  };
  auto stageV = [&](int kb, int buf) {
    const unsigned short* base = vt + (size_t)bh * 64 * T_SEQ + kb * 64;
#pragma unroll
    for (int q2 = 0; q2 < 2; ++q2) {
      int chunk = q2 * 256 + tid;
      int row = chunk >> 3, cpos = chunk & 7;
      int c = cpos ^ (row & 7);
      const unsigned short* src = base + (size_t)row * T_SEQ + c * 8;
      __builtin_amdgcn_global_load_lds(
          (const __attribute__((address_space(1))) void*)src,
          (__attribute__((address_space(3))) void*)&Vl[buf][chunk * 8], 16, 0, 0);
    }
  };

  stageK(0, 0); stageV(0, 0);

  for (int kb = 0; kb <= qb; ++kb) {
    int buf = kb & 1;
    if (kb < qb) { stageK(kb + 1, buf ^ 1); stageV(kb + 1, buf ^ 1); }
    if (kb < qb) asm volatile("s_waitcnt vmcnt(4)" ::: "memory");
    else         asm volatile("s_waitcnt vmcnt(0)" ::: "memory");
    asm volatile("s_barrier" ::: "memory");

    // ---- S = Q K^T ----
    f32x4 s[4] = {};
#pragma unroll
    for (int kk = 0; kk < 2; ++kk)
#pragma unroll
      for (int n = 0; n < 4; ++n) {
        int krow = n * 16 + l16;
        bf16x8 fb = *(const bf16x8*)((const char*)Kl[buf] + krow * 128 + (((kk * 4 + g) ^ (krow & 7)) * 16));
        s[n] = __builtin_amdgcn_mfma_f32_16x16x32_bf16(qf[kk], fb, s[n], 0, 0, 0);
      }

    // ---- online softmax (log2 domain) ----
    bool diag = (kb == qb);
    float pr[4][4];
    float corr[4];
#pragma unroll
    for (int j = 0; j < 4; ++j) {
      int rloc = w * 16 + g * 4 + j;
      float m = -3.0e38f;
#pragma unroll
      for (int n = 0; n < 4; ++n) {
        float v = s[n][j] * scale2;
        if (diag && (n * 16 + l16) > rloc) v = -3.0e38f;
        pr[n][j] = v;
        m = fmaxf(m, v);
      }
      m = fmaxf(m, __shfl_xor(m, 1));
      m = fmaxf(m, __shfl_xor(m, 2));
      m = fmaxf(m, __shfl_xor(m, 4));
      m = fmaxf(m, __shfl_xor(m, 8));
      float mn = fmaxf(mrun[j], m);
      corr[j] = exp2f(mrun[j] - mn);
      mrun[j] = mn;
      float ps = 0.f;
#pragma unroll
      for (int n = 0; n < 4; ++n) {
        float e = exp2f(pr[n][j] - mn);
        pr[n][j] = e;
        ps += e;
      }
      ps += __shfl_xor(ps, 1);
      ps += __shfl_xor(ps, 2);
      ps += __shfl_xor(ps, 4);
      ps += __shfl_xor(ps, 8);
      lrun[j] = lrun[j] * corr[j] + ps;
    }
#pragma unroll
    for (int n = 0; n < 4; ++n)
#pragma unroll
      for (int j = 0; j < 4; ++j)
        yacc[n][j] *= corr[j];

    // ---- P strip (wave-private rows) ----
#pragma unroll
    for (int j = 0; j < 4; ++j) {
      int row = w * 16 + g * 4 + j;
#pragma unroll
      for (int n = 0; n < 4; ++n)
        *(unsigned short*)(Pl + ((row * 128 + (n * 16 + l16) * 2) ^ ((row & 7) << 4))) = f2bf(pr[n][j]);
    }

    // ---- y += P V ----
#pragma unroll
    for (int kk = 0; kk < 2; ++kk) {
      int prow = w * 16 + l16;
      bf16x8 fa = *(const bf16x8*)(Pl + ((prow * 128 + (kk * 32 + g * 8) * 2) ^ ((prow & 7) << 4)));
#pragma unroll
      for (int n = 0; n < 4; ++n) {
        int vrow = n * 16 + l16;
        bf16x8 fbv = *(const bf16x8*)((const char*)Vl[buf] + vrow * 128 + (((kk * 4 + g) ^ (vrow & 7)) * 16));
        yacc[n] = __builtin_amdgcn_mfma_f32_16x16x32_bf16(fa, fbv, yacc[n], 0, 0, 0);
      }
    }
    asm volatile("s_barrier" ::: "memory");
  }

  // ---- output ----
#pragma unroll
  for (int j = 0; j < 4; ++j) {
    float inv = 1.0f / lrun[j];
    int row = qb * 64 + w * 16 + g * 4 + j;
    unsigned short* yo = y + (bT + row) * C_DIM + h * 64;
#pragma unroll
    for (int n = 0; n < 4; ++n)
      yo[n * 16 + l16] = f2bf(yacc[n][j] * inv);
  }
}

extern "C" void kernel_launch(void* const* d_in, const int* in_sizes, int n_in,
                              void* d_out, int out_size, void* d_ws, size_t ws_size,
                              hipStream_t stream) {
  const int*   x    = (const int*)d_in[0];
  const float* tok  = (const float*)d_in[1];
  const float* pos  = (const float*)d_in[2];
  const float* wq   = (const float*)d_in[3];
  const float* bq   = (const float*)d_in[4];
  const float* wk   = (const float*)d_in[5];
  const float* bk   = (const float*)d_in[6];
  const float* wv   = (const float*)d_in[7];
  const float* bv   = (const float*)d_in[8];
  const float* wh   = (const float*)d_in[9];
  const float* bhd  = (const float*)d_in[10];
  float* out = (float*)d_out;

  char* ws = (char*)d_ws;
  size_t off = 0;
  auto alloc = [&](size_t bytes) {
    void* p = ws + off;
    off += (bytes + 255) & ~(size_t)255;
    return p;
  };
  unsigned short* h_bf    = (unsigned short*)alloc((size_t)4096 * 1024 * 2);
  unsigned short* wqkv_t  = (unsigned short*)alloc((size_t)3072 * 1024 * 2);
  float*          qbias   = (float*)alloc((size_t)3072 * 4);
  unsigned short* wh_t    = (unsigned short*)alloc((size_t)V_DIM * 1024 * 2);
  unsigned short* qkv_bf  = (unsigned short*)alloc((size_t)4096 * 3072 * 2);
  unsigned short* vtb     = (unsigned short*)alloc((size_t)32 * 64 * T_SEQ * 2);
  unsigned short* ybf     = (unsigned short*)alloc((size_t)4096 * 1024 * 2);

  embed_kernel<<<4096, 256, 0, stream>>>(x, tok, pos, h_bf);
  repack_qkv<<<dim3(4096, 3), 256, 0, stream>>>(wq, wk, wv, bq, bk, bv, wqkv_t, qbias);
  repack_whead<<<dim3(V_DIM / 64, 16), 256, 0, stream>>>(wh, wh_t);
  // QKV proj (bf16 out, V written transposed to vtb): 768 blocks
  gemm_bf16_o16<<<768, 256, 0, stream>>>(h_bf, wqkv_t, qbias, qkv_bf, vtb, 3072, 32);
  attn_mfma<<<dim3(T_SEQ / 64, 2 * H_N), 256, 0, stream>>>(qkv_bf, vtb, ybf);
  // head: M=4096, N=32000 -> 16 x 125 = 2000 blocks (%8==0)
  gemm256<<<2000, 512, 0, stream>>>(ybf, wh_t, bhd, out, V_DIM, 16);
}

// Round 15
// 591.451 us; speedup vs baseline: 1.0347x; 1.0215x over previous
//
#include <hip/hip_runtime.h>

#define T_SEQ 2048
#define C_DIM 1024
#define H_N   16
#define HS_D  64
#define V_DIM 32000

typedef float f32x4 __attribute__((ext_vector_type(4)));
typedef __bf16 bf16x8 __attribute__((ext_vector_type(8)));
typedef unsigned short us4 __attribute__((ext_vector_type(4)));
typedef unsigned short us8 __attribute__((ext_vector_type(8)));

__device__ inline unsigned short f2bf(float f) {
  unsigned int u = __float_as_uint(f);
  u = (u + 0x7FFFu + ((u >> 16) & 1u)) >> 16;
  return (unsigned short)u;
}

// ---------------- embed: h = tok_emb[x] + pos_emb, cast to bf16 ----------------
__global__ __launch_bounds__(256) void embed_kernel(
    const int* __restrict__ x, const float* __restrict__ tok,
    const float* __restrict__ pos, unsigned short* __restrict__ h) {
  int idx = blockIdx.x * 256 + threadIdx.x;   // over (B*T*C)/4
  int bt = idx >> 8;                          // 256 float4 per row
  int c4 = (idx & 255) * 4;
  int t = bt & (T_SEQ - 1);
  int tokid = x[bt];
  f32x4 a = *(const f32x4*)(tok + (size_t)tokid * C_DIM + c4);
  f32x4 b = *(const f32x4*)(pos + (size_t)t * C_DIM + c4);
  f32x4 s = a + b;
  us4 o;
  o[0] = f2bf(s[0]); o[1] = f2bf(s[1]); o[2] = f2bf(s[2]); o[3] = f2bf(s[3]);
  *(us4*)(h + (size_t)bt * C_DIM + c4) = o;
}

// ------------- repack wq/wk/wv [H,C,HS] f32 -> bf16 [3072][1024] (N,K) -------------
__global__ __launch_bounds__(256) void repack_qkv(
    const float* __restrict__ wq, const float* __restrict__ wk, const float* __restrict__ wv,
    const float* __restrict__ bq, const float* __restrict__ bk, const float* __restrict__ bv,
    unsigned short* __restrict__ wt, float* __restrict__ biasp) {
  int which = blockIdx.y;
  const float* w = (which == 0) ? wq : (which == 1) ? wk : wv;
  int i = blockIdx.x * 256 + threadIdx.x;   // 0 .. H*C*HS (=1M)
  int d = i & 63;
  int c = (i >> 6) & (C_DIM - 1);
  int hh = i >> 16;
  int n = which * 1024 + hh * 64 + d;
  wt[(size_t)n * C_DIM + c] = f2bf(w[i]);
  if (c == 0) {
    const float* bb = (which == 0) ? bq : (which == 1) ? bk : bv;
    biasp[n] = bb[hh * 64 + d];
  }
}

// ------------- transpose-repack w_head [C,V] f32 -> bf16 [V][C], vectorized -------------
__global__ __launch_bounds__(256) void repack_whead(
    const float* __restrict__ wh, unsigned short* __restrict__ wht) {
  __shared__ float tile[64][65];
  int v0 = blockIdx.x * 64;
  int c0 = blockIdx.y * 64;
  int tr = threadIdx.x >> 4;         // 0..15
  int tc = (threadIdx.x & 15) * 4;   // 0,4,..,60
#pragma unroll
  for (int i = 0; i < 4; ++i) {
    int r = i * 16 + tr;             // c-row
    *(f32x4*)&tile[r][tc] = *(const f32x4*)&wh[(size_t)(c0 + r) * V_DIM + v0 + tc];
  }
  __syncthreads();
#pragma unroll
  for (int i = 0; i < 4; ++i) {
    int vr = i * 16 + tr;            // v-row
    us4 o;
#pragma unroll
    for (int k = 0; k < 4; ++k) o[k] = f2bf(tile[tc + k][vr]);
    *(us4*)&wht[(size_t)(v0 + vr) * C_DIM + c0 + tc] = o;
  }
}

// ------------- 128x128 4-wave QKV GEMM, bf16 out, V-transpose fused -------------
__global__ __launch_bounds__(256) void gemm_bf16_o16(
    const unsigned short* __restrict__ A, const unsigned short* __restrict__ Bt,
    const float* __restrict__ bias, unsigned short* __restrict__ Cout,
    unsigned short* __restrict__ vt, int N, int Mtiles) {
  const int K = 1024;
  __shared__ unsigned short As[128 * 32];
  __shared__ unsigned short Bs[128 * 32];
  int tid = threadIdx.x;
  int lane = tid & 63, wvi = tid >> 6;
  int cpx = gridDim.x >> 3;
  int lin = blockIdx.x;
  int wg = (lin & 7) * cpx + (lin >> 3);
  int m0 = (wg % Mtiles) * 128;
  int n0 = (wg / Mtiles) * 128;
  int wmm = (wvi >> 1) * 64, wnn = (wvi & 1) * 64;
  int r16 = lane & 15, gg = lane >> 4;
  f32x4 acc[4][4] = {};

  for (int k0 = 0; k0 < K; k0 += 32) {
#pragma unroll
    for (int it = 0; it < 2; ++it) {
      int ch = it * 256 + wvi * 64 + lane;
      int row = ch >> 2, cc = (ch & 3) * 8;
      const unsigned short* ga = A + (size_t)(m0 + row) * K + k0 + cc;
      __builtin_amdgcn_global_load_lds(
          (const __attribute__((address_space(1))) void*)ga,
          (__attribute__((address_space(3))) void*)&As[ch * 8], 16, 0, 0);
      const unsigned short* gb = Bt + (size_t)(n0 + row) * K + k0 + cc;
      __builtin_amdgcn_global_load_lds(
          (const __attribute__((address_space(1))) void*)gb,
          (__attribute__((address_space(3))) void*)&Bs[ch * 8], 16, 0, 0);
    }
    __syncthreads();
    bf16x8 fa[4], fb[4];
#pragma unroll
    for (int m = 0; m < 4; ++m)
      fa[m] = *(const bf16x8*)&As[(wmm + m * 16 + r16) * 32 + gg * 8];
#pragma unroll
    for (int n = 0; n < 4; ++n)
      fb[n] = *(const bf16x8*)&Bs[(wnn + n * 16 + r16) * 32 + gg * 8];
#pragma unroll
    for (int m = 0; m < 4; ++m)
#pragma unroll
      for (int n = 0; n < 4; ++n)
        acc[m][n] = __builtin_amdgcn_mfma_f32_16x16x32_bf16(fa[m], fb[n], acc[m][n], 0, 0, 0);
    __syncthreads();
  }
#pragma unroll
  for (int m = 0; m < 4; ++m) {
    int row = m0 + wmm + m * 16 + gg * 4;
#pragma unroll
    for (int n = 0; n < 4; ++n) {
      int col = n0 + wnn + n * 16 + r16;
      float bval = bias[col];
      if (n0 < 2048) {   // Q/K tile (uniform branch; n0 multiple of 128)
#pragma unroll
        for (int j = 0; j < 4; ++j)
          Cout[(size_t)(row + j) * N + col] = f2bf(acc[m][n][j] + bval);
      } else {           // V tile -> transposed vt[b*16+h][d][t]
        int d = (col - 2048) & 63, hh = (col - 2048) >> 6;
        int b = row >> 11, t0 = row & 2047;
        us4 o;
#pragma unroll
        for (int j = 0; j < 4; ++j) o[j] = f2bf(acc[m][n][j] + bval);
        *(us4*)&vt[((size_t)(b * 16 + hh) * 64 + d) * T_SEQ + t0] = o;
      }
    }
  }
}

// ------------- 256x256 double-buffered 2-phase GEMM (R7 schedule, frozen) -------------
// NO XCD swizzle: identity block order, m-tile fastest. Consecutive blocks (one
// B n-panel x 16 m-tiles) round-robin across the 8 XCDs, so all XCDs co-stream
// the SAME B panel through the shared L3 (B=65 MB is L3-fit) -> B fetched ~once
// from HBM instead of once per XCD-chunk (R14: FETCH 355 MB at 5x B re-fetch).
#define GK 1024
#define GNT 16   // K / 64

__global__ __launch_bounds__(512, 1) void gemm256(
    const unsigned short* __restrict__ A, const unsigned short* __restrict__ Bt,
    const float* __restrict__ bias, float* __restrict__ Cout, int N, int Mtiles) {
  __shared__ unsigned short As[2][256 * 64];
  __shared__ unsigned short Bs[2][256 * 64];
  int tid = threadIdx.x;
  int lane = tid & 63;
  int wid = tid >> 6;
  int wm = wid >> 2, wn = wid & 3;
  int l16 = lane & 15, g = lane >> 4;
  int swz = l16 & 7;

  int wg = blockIdx.x;               // identity mapping (no XCD chunking)
  int m0 = (wg % Mtiles) * 256;
  int n0 = (wg / Mtiles) * 256;

  auto stageA2 = [&](int kt, int mh) {
    unsigned short* lds = As[kt & 1];
#pragma unroll
    for (int q = 0; q < 2; ++q) {
      int chunk = q * 512 + tid;
      int rr = chunk >> 3;
      int row = (rr & 63) + ((rr >> 6) << 7) + mh * 64;
      int cpos = chunk & 7;
      int c = cpos ^ (row & 7);
      const unsigned short* src = A + (size_t)(m0 + row) * GK + kt * 64 + c * 8;
      __builtin_amdgcn_global_load_lds(
          (const __attribute__((address_space(1))) void*)src,
          (__attribute__((address_space(3))) void*)(lds + row * 64 + cpos * 8), 16, 0, 0);
    }
  };
  auto stageB4 = [&](int kt) {
    unsigned short* lds = Bs[kt & 1];
#pragma unroll
    for (int q = 0; q < 4; ++q) {
      int chunk = q * 512 + tid;
      int row = chunk >> 3;
      int cpos = chunk & 7;
      int c = cpos ^ (row & 7);
      const unsigned short* src = Bt + (size_t)(n0 + row) * GK + kt * 64 + c * 8;
      __builtin_amdgcn_global_load_lds(
          (const __attribute__((address_space(1))) void*)src,
          (__attribute__((address_space(3))) void*)(lds + row * 64 + cpos * 8), 16, 0, 0);
    }
  };

  stageA2(0, 0); stageB4(0);
  stageA2(0, 1);
  stageA2(1, 0); stageB4(1);
  asm volatile("s_waitcnt vmcnt(8)" ::: "memory");
  asm volatile("s_barrier" ::: "memory");

  f32x4 acc[8][4] = {};

  for (int t = 0; t < GNT; ++t) {
    const char* Ab = (const char*)As[t & 1];
    const char* Bb = (const char*)Bs[t & 1];
    bf16x8 bA[4][2], bB[4][2];

#pragma unroll
    for (int mi = 0; mi < 4; ++mi) {
      int row = wm * 128 + mi * 16 + l16;
#pragma unroll
      for (int kk = 0; kk < 2; ++kk)
        bA[mi][kk] = *(const bf16x8*)(Ab + row * 128 + (((kk * 4 + g) ^ swz) * 16));
    }
#pragma unroll
    for (int ni = 0; ni < 4; ++ni) {
      int row = wn * 64 + ni * 16 + l16;
#pragma unroll
      for (int kk = 0; kk < 2; ++kk)
        bB[ni][kk] = *(const bf16x8*)(Bb + row * 128 + (((kk * 4 + g) ^ swz) * 16));
    }
    if (t + 1 < GNT) stageA2(t + 1, 1);
    asm volatile("s_barrier" ::: "memory");
    asm volatile("s_waitcnt lgkmcnt(0)" ::: "memory");
    __builtin_amdgcn_sched_barrier(0);
    __builtin_amdgcn_s_setprio(1);
#pragma unroll
    for (int mi = 0; mi < 4; ++mi)
#pragma unroll
      for (int ni = 0; ni < 4; ++ni)
#pragma unroll
        for (int kk = 0; kk < 2; ++kk)
          acc[mi][ni] = __builtin_amdgcn_mfma_f32_16x16x32_bf16(bB[ni][kk], bA[mi][kk], acc[mi][ni], 0, 0, 0);
    __builtin_amdgcn_s_setprio(0);
    if (t + 1 < GNT) asm volatile("s_waitcnt vmcnt(8)" ::: "memory");
    else             asm volatile("s_waitcnt vmcnt(0)" ::: "memory");
    asm volatile("s_barrier" ::: "memory");

#pragma unroll
    for (int mi = 0; mi < 4; ++mi) {
      int row = wm * 128 + 64 + mi * 16 + l16;
#pragma unroll
      for (int kk = 0; kk < 2; ++kk)
        bA[mi][kk] = *(const bf16x8*)(Ab + row * 128 + (((kk * 4 + g) ^ swz) * 16));
    }
    if (t + 2 < GNT) { stageA2(t + 2, 0); stageB4(t + 2); }
    asm volatile("s_barrier" ::: "memory");
    asm volatile("s_waitcnt lgkmcnt(0)" ::: "memory");
    __builtin_amdgcn_sched_barrier(0);
    __builtin_amdgcn_s_setprio(1);
#pragma unroll
    for (int mi = 0; mi < 4; ++mi)
#pragma unroll
      for (int ni = 0; ni < 4; ++ni)
#pragma unroll
        for (int kk = 0; kk < 2; ++kk)
          acc[4 + mi][ni] = __builtin_amdgcn_mfma_f32_16x16x32_bf16(bB[ni][kk], bA[mi][kk], acc[4 + mi][ni], 0, 0, 0);
    __builtin_amdgcn_s_setprio(0);
    if (t + 2 < GNT)       asm volatile("s_waitcnt vmcnt(8)" ::: "memory");
    else if (t + 2 == GNT) asm volatile("s_waitcnt vmcnt(2)" ::: "memory");
    asm volatile("s_barrier" ::: "memory");
  }

  // ---- epilogue: coalesced f32x4 normal stores ----
#pragma unroll
  for (int mf = 0; mf < 8; ++mf) {
    int row = m0 + wm * 128 + mf * 16 + l16;
    float* outp = Cout + (size_t)row * N + n0 + wn * 64;
#pragma unroll
    for (int ni = 0; ni < 4; ++ni) {
      f32x4 v = acc[mf][ni];
      f32x4 bv = *(const f32x4*)&bias[n0 + wn * 64 + ni * 16 + g * 4];
      v += bv;
      *(f32x4*)(outp + ni * 16 + g * 4) = v;
    }
  }
}

// ------------- MFMA flash attention, bf16 in, DMA-staged, double-buffered -------------
__global__ __launch_bounds__(256) void attn_mfma(
    const unsigned short* __restrict__ qkv, const unsigned short* __restrict__ vt,
    unsigned short* __restrict__ y) {
  __shared__ unsigned short Kl[2][4096];
  __shared__ unsigned short Vl[2][4096];
  __shared__ char Pl[8192];

  int bh = blockIdx.y;
  int b = bh >> 4, h = bh & 15;
  int qb = (T_SEQ / 64 - 1) - blockIdx.x;
  int tid = threadIdx.x;
  int lane = tid & 63, w = tid >> 6;
  int l16 = lane & 15, g = lane >> 4;
  size_t bT = (size_t)b * T_SEQ;
  const float scale2 = 0.03125f * 1.44269504f;  // C^-0.5 * log2(e)

  const unsigned short* qrow = qkv + (bT + qb * 64 + w * 16 + l16) * 3072 + h * 64;
  bf16x8 qf[2] = { *(const bf16x8*)(qrow + g * 8), *(const bf16x8*)(qrow + 32 + g * 8) };

  f32x4 yacc[4] = {};
  float mrun[4], lrun[4];
#pragma unroll
  for (int j = 0; j < 4; ++j) { mrun[j] = -3.0e38f; lrun[j] = 0.f; }

  auto stageK = [&](int kb, int buf) {
    const unsigned short* base = qkv + (bT + kb * 64) * 3072 + 1024 + h * 64;
#pragma unroll
    for (int q2 = 0; q2 < 2; ++q2) {
      int chunk = q2 * 256 + tid;
      int row = chunk >> 3, cpos = chunk & 7;
      int c = cpos ^ (row & 7);
      const unsigned short* src = base + (size_t)row * 3072 + c * 8;
      __builtin_amdgcn_global_load_lds(
          (const __attribute__((address_space(1))) void*)src,
          (__attribute__((address_space(3))) void*)&Kl[buf][chunk * 8], 16, 0, 0);
    }
  };
  auto stageV = [&](int kb, int buf) {
    const unsigned short* base = vt + (size_t)bh * 64 * T_SEQ + kb * 64;
#pragma unroll
    for (int q2 = 0; q2 < 2; ++q2) {
      int chunk = q2 * 256 + tid;
      int row = chunk >> 3, cpos = chunk & 7;
      int c = cpos ^ (row & 7);
      const unsigned short* src = base + (size_t)row * T_SEQ + c * 8;
      __builtin_amdgcn_global_load_lds(
          (const __attribute__((address_space(1))) void*)src,
          (__attribute__((address_space(3))) void*)&Vl[buf][chunk * 8], 16, 0, 0);
    }
  };

  stageK(0, 0); stageV(0, 0);

  for (int kb = 0; kb <= qb; ++kb) {
    int buf = kb & 1;
    if (kb < qb) { stageK(kb + 1, buf ^ 1); stageV(kb + 1, buf ^ 1); }
    if (kb < qb) asm volatile("s_waitcnt vmcnt(4)" ::: "memory");
    else         asm volatile("s_waitcnt vmcnt(0)" ::: "memory");
    asm volatile("s_barrier" ::: "memory");

    // ---- S = Q K^T ----
    f32x4 s[4] = {};
#pragma unroll
    for (int kk = 0; kk < 2; ++kk)
#pragma unroll
      for (int n = 0; n < 4; ++n) {
        int krow = n * 16 + l16;
        bf16x8 fb = *(const bf16x8*)((const char*)Kl[buf] + krow * 128 + (((kk * 4 + g) ^ (krow & 7)) * 16));
        s[n] = __builtin_amdgcn_mfma_f32_16x16x32_bf16(qf[kk], fb, s[n], 0, 0, 0);
      }

    // ---- online softmax (log2 domain) ----
    bool diag = (kb == qb);
    float pr[4][4];
    float corr[4];
#pragma unroll
    for (int j = 0; j < 4; ++j) {
      int rloc = w * 16 + g * 4 + j;
      float m = -3.0e38f;
#pragma unroll
      for (int n = 0; n < 4; ++n) {
        float v = s[n][j] * scale2;
        if (diag && (n * 16 + l16) > rloc) v = -3.0e38f;
        pr[n][j] = v;
        m = fmaxf(m, v);
      }
      m = fmaxf(m, __shfl_xor(m, 1));
      m = fmaxf(m, __shfl_xor(m, 2));
      m = fmaxf(m, __shfl_xor(m, 4));
      m = fmaxf(m, __shfl_xor(m, 8));
      float mn = fmaxf(mrun[j], m);
      corr[j] = exp2f(mrun[j] - mn);
      mrun[j] = mn;
      float ps = 0.f;
#pragma unroll
      for (int n = 0; n < 4; ++n) {
        float e = exp2f(pr[n][j] - mn);
        pr[n][j] = e;
        ps += e;
      }
      ps += __shfl_xor(ps, 1);
      ps += __shfl_xor(ps, 2);
      ps += __shfl_xor(ps, 4);
      ps += __shfl_xor(ps, 8);
      lrun[j] = lrun[j] * corr[j] + ps;
    }
#pragma unroll
    for (int n = 0; n < 4; ++n)
#pragma unroll
      for (int j = 0; j < 4; ++j)
        yacc[n][j] *= corr[j];

    // ---- P strip (wave-private rows) ----
#pragma unroll
    for (int j = 0; j < 4; ++j) {
      int row = w * 16 + g * 4 + j;
#pragma unroll
      for (int n = 0; n < 4; ++n)
        *(unsigned short*)(Pl + ((row * 128 + (n * 16 + l16) * 2) ^ ((row & 7) << 4))) = f2bf(pr[n][j]);
    }

    // ---- y += P V ----
#pragma unroll
    for (int kk = 0; kk < 2; ++kk) {
      int prow = w * 16 + l16;
      bf16x8 fa = *(const bf16x8*)(Pl + ((prow * 128 + (kk * 32 + g * 8) * 2) ^ ((prow & 7) << 4)));
#pragma unroll
      for (int n = 0; n < 4; ++n) {
        int vrow = n * 16 + l16;
        bf16x8 fbv = *(const bf16x8*)((const char*)Vl[buf] + vrow * 128 + (((kk * 4 + g) ^ (vrow & 7)) * 16));
        yacc[n] = __builtin_amdgcn_mfma_f32_16x16x32_bf16(fa, fbv, yacc[n], 0, 0, 0);
      }
    }
    asm volatile("s_barrier" ::: "memory");
  }

  // ---- output ----
#pragma unroll
  for (int j = 0; j < 4; ++j) {
    float inv = 1.0f / lrun[j];
    int row = qb * 64 + w * 16 + g * 4 + j;
    unsigned short* yo = y + (bT + row) * C_DIM + h * 64;
#pragma unroll
    for (int n = 0; n < 4; ++n)
      yo[n * 16 + l16] = f2bf(yacc[n][j] * inv);
  }
}

extern "C" void kernel_launch(void* const* d_in, const int* in_sizes, int n_in,
                              void* d_out, int out_size, void* d_ws, size_t ws_size,
                              hipStream_t stream) {
  const int*   x    = (const int*)d_in[0];
  const float* tok  = (const float*)d_in[1];
  const float* pos  = (const float*)d_in[2];
  const float* wq   = (const float*)d_in[3];
  const float* bq   = (const float*)d_in[4];
  const float* wk   = (const float*)d_in[5];
  const float* bk   = (const float*)d_in[6];
  const float* wv   = (const float*)d_in[7];
  const float* bv   = (const float*)d_in[8];
  const float* wh   = (const float*)d_in[9];
  const float* bhd  = (const float*)d_in[10];
  float* out = (float*)d_out;

  char* ws = (char*)d_ws;
  size_t off = 0;
  auto alloc = [&](size_t bytes) {
    void* p = ws + off;
    off += (bytes + 255) & ~(size_t)255;
    return p;
  };
  unsigned short* h_bf    = (unsigned short*)alloc((size_t)4096 * 1024 * 2);
  unsigned short* wqkv_t  = (unsigned short*)alloc((size_t)3072 * 1024 * 2);
  float*          qbias   = (float*)alloc((size_t)3072 * 4);
  unsigned short* wh_t    = (unsigned short*)alloc((size_t)V_DIM * 1024 * 2);
  unsigned short* qkv_bf  = (unsigned short*)alloc((size_t)4096 * 3072 * 2);
  unsigned short* vtb     = (unsigned short*)alloc((size_t)32 * 64 * T_SEQ * 2);
  unsigned short* ybf     = (unsigned short*)alloc((size_t)4096 * 1024 * 2);

  embed_kernel<<<4096, 256, 0, stream>>>(x, tok, pos, h_bf);
  repack_qkv<<<dim3(4096, 3), 256, 0, stream>>>(wq, wk, wv, bq, bk, bv, wqkv_t, qbias);
  repack_whead<<<dim3(V_DIM / 64, 16), 256, 0, stream>>>(wh, wh_t);
  // QKV proj (bf16 out, V written transposed to vtb): 768 blocks
  gemm_bf16_o16<<<768, 256, 0, stream>>>(h_bf, wqkv_t, qbias, qkv_bf, vtb, 3072, 32);
  attn_mfma<<<dim3(T_SEQ / 64, 2 * H_N), 256, 0, stream>>>(qkv_bf, vtb, ybf);
  // head: M=4096, N=32000 -> 2000 blocks, identity order (L3 co-streaming)
  gemm256<<<2000, 512, 0, stream>>>(ybf, wh_t, bhd, out, V_DIM, 16);
}

// Round 16
// 564.943 us; speedup vs baseline: 1.0833x; 1.0469x over previous
//
#include <hip/hip_runtime.h>

#define T_SEQ 2048
#define C_DIM 1024
#define H_N   16
#define HS_D  64
#define V_DIM 32000

typedef float f32x4 __attribute__((ext_vector_type(4)));
typedef __bf16 bf16x8 __attribute__((ext_vector_type(8)));
typedef unsigned short us4 __attribute__((ext_vector_type(4)));
typedef unsigned short us8 __attribute__((ext_vector_type(8)));

__device__ inline unsigned short f2bf(float f) {
  unsigned int u = __float_as_uint(f);
  u = (u + 0x7FFFu + ((u >> 16) & 1u)) >> 16;
  return (unsigned short)u;
}

// ---------------- embed: h = tok_emb[x] + pos_emb, cast to bf16 ----------------
__global__ __launch_bounds__(256) void embed_kernel(
    const int* __restrict__ x, const float* __restrict__ tok,
    const float* __restrict__ pos, unsigned short* __restrict__ h) {
  int idx = blockIdx.x * 256 + threadIdx.x;   // over (B*T*C)/4
  int bt = idx >> 8;                          // 256 float4 per row
  int c4 = (idx & 255) * 4;
  int t = bt & (T_SEQ - 1);
  int tokid = x[bt];
  f32x4 a = *(const f32x4*)(tok + (size_t)tokid * C_DIM + c4);
  f32x4 b = *(const f32x4*)(pos + (size_t)t * C_DIM + c4);
  f32x4 s = a + b;
  us4 o;
  o[0] = f2bf(s[0]); o[1] = f2bf(s[1]); o[2] = f2bf(s[2]); o[3] = f2bf(s[3]);
  *(us4*)(h + (size_t)bt * C_DIM + c4) = o;
}

// ------------- repack wq/wk/wv [H,C,HS] f32 -> bf16 [3072][1024] (N,K) -------------
__global__ __launch_bounds__(256) void repack_qkv(
    const float* __restrict__ wq, const float* __restrict__ wk, const float* __restrict__ wv,
    const float* __restrict__ bq, const float* __restrict__ bk, const float* __restrict__ bv,
    unsigned short* __restrict__ wt, float* __restrict__ biasp) {
  int which = blockIdx.y;
  const float* w = (which == 0) ? wq : (which == 1) ? wk : wv;
  int i = blockIdx.x * 256 + threadIdx.x;   // 0 .. H*C*HS (=1M)
  int d = i & 63;
  int c = (i >> 6) & (C_DIM - 1);
  int hh = i >> 16;
  int n = which * 1024 + hh * 64 + d;
  wt[(size_t)n * C_DIM + c] = f2bf(w[i]);
  if (c == 0) {
    const float* bb = (which == 0) ? bq : (which == 1) ? bk : bv;
    biasp[n] = bb[hh * 64 + d];
  }
}

// ------------- transpose-repack w_head [C,V] f32 -> bf16 [V][C], vectorized -------------
__global__ __launch_bounds__(256) void repack_whead(
    const float* __restrict__ wh, unsigned short* __restrict__ wht) {
  __shared__ float tile[64][65];
  int v0 = blockIdx.x * 64;
  int c0 = blockIdx.y * 64;
  int tr = threadIdx.x >> 4;         // 0..15
  int tc = (threadIdx.x & 15) * 4;   // 0,4,..,60
#pragma unroll
  for (int i = 0; i < 4; ++i) {
    int r = i * 16 + tr;             // c-row
    *(f32x4*)&tile[r][tc] = *(const f32x4*)&wh[(size_t)(c0 + r) * V_DIM + v0 + tc];
  }
  __syncthreads();
#pragma unroll
  for (int i = 0; i < 4; ++i) {
    int vr = i * 16 + tr;            // v-row
    us4 o;
#pragma unroll
    for (int k = 0; k < 4; ++k) o[k] = f2bf(tile[tc + k][vr]);
    *(us4*)&wht[(size_t)(v0 + vr) * C_DIM + c0 + tc] = o;
  }
}

// ------------- 128x128 4-wave QKV GEMM, bf16 out, V-transpose fused -------------
__global__ __launch_bounds__(256) void gemm_bf16_o16(
    const unsigned short* __restrict__ A, const unsigned short* __restrict__ Bt,
    const float* __restrict__ bias, unsigned short* __restrict__ Cout,
    unsigned short* __restrict__ vt, int N, int Mtiles) {
  const int K = 1024;
  __shared__ unsigned short As[128 * 32];
  __shared__ unsigned short Bs[128 * 32];
  int tid = threadIdx.x;
  int lane = tid & 63, wvi = tid >> 6;
  int cpx = gridDim.x >> 3;
  int lin = blockIdx.x;
  int wg = (lin & 7) * cpx + (lin >> 3);
  int m0 = (wg % Mtiles) * 128;
  int n0 = (wg / Mtiles) * 128;
  int wmm = (wvi >> 1) * 64, wnn = (wvi & 1) * 64;
  int r16 = lane & 15, gg = lane >> 4;
  f32x4 acc[4][4] = {};

  for (int k0 = 0; k0 < K; k0 += 32) {
#pragma unroll
    for (int it = 0; it < 2; ++it) {
      int ch = it * 256 + wvi * 64 + lane;
      int row = ch >> 2, cc = (ch & 3) * 8;
      const unsigned short* ga = A + (size_t)(m0 + row) * K + k0 + cc;
      __builtin_amdgcn_global_load_lds(
          (const __attribute__((address_space(1))) void*)ga,
          (__attribute__((address_space(3))) void*)&As[ch * 8], 16, 0, 0);
      const unsigned short* gb = Bt + (size_t)(n0 + row) * K + k0 + cc;
      __builtin_amdgcn_global_load_lds(
          (const __attribute__((address_space(1))) void*)gb,
          (__attribute__((address_space(3))) void*)&Bs[ch * 8], 16, 0, 0);
    }
    __syncthreads();
    bf16x8 fa[4], fb[4];
#pragma unroll
    for (int m = 0; m < 4; ++m)
      fa[m] = *(const bf16x8*)&As[(wmm + m * 16 + r16) * 32 + gg * 8];
#pragma unroll
    for (int n = 0; n < 4; ++n)
      fb[n] = *(const bf16x8*)&Bs[(wnn + n * 16 + r16) * 32 + gg * 8];
#pragma unroll
    for (int m = 0; m < 4; ++m)
#pragma unroll
      for (int n = 0; n < 4; ++n)
        acc[m][n] = __builtin_amdgcn_mfma_f32_16x16x32_bf16(fa[m], fb[n], acc[m][n], 0, 0, 0);
    __syncthreads();
  }
#pragma unroll
  for (int m = 0; m < 4; ++m) {
    int row = m0 + wmm + m * 16 + gg * 4;
#pragma unroll
    for (int n = 0; n < 4; ++n) {
      int col = n0 + wnn + n * 16 + r16;
      float bval = bias[col];
      if (n0 < 2048) {   // Q/K tile (uniform branch; n0 multiple of 128)
#pragma unroll
        for (int j = 0; j < 4; ++j)
          Cout[(size_t)(row + j) * N + col] = f2bf(acc[m][n][j] + bval);
      } else {           // V tile -> transposed vt[b*16+h][d][t]
        int d = (col - 2048) & 63, hh = (col - 2048) >> 6;
        int b = row >> 11, t0 = row & 2047;
        us4 o;
#pragma unroll
        for (int j = 0; j < 4; ++j) o[j] = f2bf(acc[m][n][j] + bval);
        *(us4*)&vt[((size_t)(b * 16 + hh) * 64 + d) * T_SEQ + t0] = o;
      }
    }
  }
}

// ------------- 256x256 double-buffered 2-phase GEMM (R7 schedule, frozen) -------------
// Identity block order (R15: FETCH 355->289 MB vs XCD-chunked; dur same or better).
#define GK 1024
#define GNT 16   // K / 64

__global__ __launch_bounds__(512, 1) void gemm256(
    const unsigned short* __restrict__ A, const unsigned short* __restrict__ Bt,
    const float* __restrict__ bias, float* __restrict__ Cout, int N, int Mtiles) {
  __shared__ unsigned short As[2][256 * 64];
  __shared__ unsigned short Bs[2][256 * 64];
  int tid = threadIdx.x;
  int lane = tid & 63;
  int wid = tid >> 6;
  int wm = wid >> 2, wn = wid & 3;
  int l16 = lane & 15, g = lane >> 4;
  int swz = l16 & 7;

  int wg = blockIdx.x;               // identity mapping (no XCD chunking)
  int m0 = (wg % Mtiles) * 256;
  int n0 = (wg / Mtiles) * 256;

  auto stageA2 = [&](int kt, int mh) {
    unsigned short* lds = As[kt & 1];
#pragma unroll
    for (int q = 0; q < 2; ++q) {
      int chunk = q * 512 + tid;
      int rr = chunk >> 3;
      int row = (rr & 63) + ((rr >> 6) << 7) + mh * 64;
      int cpos = chunk & 7;
      int c = cpos ^ (row & 7);
      const unsigned short* src = A + (size_t)(m0 + row) * GK + kt * 64 + c * 8;
      __builtin_amdgcn_global_load_lds(
          (const __attribute__((address_space(1))) void*)src,
          (__attribute__((address_space(3))) void*)(lds + row * 64 + cpos * 8), 16, 0, 0);
    }
  };
  auto stageB4 = [&](int kt) {
    unsigned short* lds = Bs[kt & 1];
#pragma unroll
    for (int q = 0; q < 4; ++q) {
      int chunk = q * 512 + tid;
      int row = chunk >> 3;
      int cpos = chunk & 7;
      int c = cpos ^ (row & 7);
      const unsigned short* src = Bt + (size_t)(n0 + row) * GK + kt * 64 + c * 8;
      __builtin_amdgcn_global_load_lds(
          (const __attribute__((address_space(1))) void*)src,
          (__attribute__((address_space(3))) void*)(lds + row * 64 + cpos * 8), 16, 0, 0);
    }
  };

  stageA2(0, 0); stageB4(0);
  stageA2(0, 1);
  stageA2(1, 0); stageB4(1);
  asm volatile("s_waitcnt vmcnt(8)" ::: "memory");
  asm volatile("s_barrier" ::: "memory");

  f32x4 acc[8][4] = {};

  for (int t = 0; t < GNT; ++t) {
    const char* Ab = (const char*)As[t & 1];
    const char* Bb = (const char*)Bs[t & 1];
    bf16x8 bA[4][2], bB[4][2];

#pragma unroll
    for (int mi = 0; mi < 4; ++mi) {
      int row = wm * 128 + mi * 16 + l16;
#pragma unroll
      for (int kk = 0; kk < 2; ++kk)
        bA[mi][kk] = *(const bf16x8*)(Ab + row * 128 + (((kk * 4 + g) ^ swz) * 16));
    }
#pragma unroll
    for (int ni = 0; ni < 4; ++ni) {
      int row = wn * 64 + ni * 16 + l16;
#pragma unroll
      for (int kk = 0; kk < 2; ++kk)
        bB[ni][kk] = *(const bf16x8*)(Bb + row * 128 + (((kk * 4 + g) ^ swz) * 16));
    }
    if (t + 1 < GNT) stageA2(t + 1, 1);
    asm volatile("s_barrier" ::: "memory");
    asm volatile("s_waitcnt lgkmcnt(0)" ::: "memory");
    __builtin_amdgcn_sched_barrier(0);
    __builtin_amdgcn_s_setprio(1);
#pragma unroll
    for (int mi = 0; mi < 4; ++mi)
#pragma unroll
      for (int ni = 0; ni < 4; ++ni)
#pragma unroll
        for (int kk = 0; kk < 2; ++kk)
          acc[mi][ni] = __builtin_amdgcn_mfma_f32_16x16x32_bf16(bB[ni][kk], bA[mi][kk], acc[mi][ni], 0, 0, 0);
    __builtin_amdgcn_s_setprio(0);
    if (t + 1 < GNT) asm volatile("s_waitcnt vmcnt(8)" ::: "memory");
    else             asm volatile("s_waitcnt vmcnt(0)" ::: "memory");
    asm volatile("s_barrier" ::: "memory");

#pragma unroll
    for (int mi = 0; mi < 4; ++mi) {
      int row = wm * 128 + 64 + mi * 16 + l16;
#pragma unroll
      for (int kk = 0; kk < 2; ++kk)
        bA[mi][kk] = *(const bf16x8*)(Ab + row * 128 + (((kk * 4 + g) ^ swz) * 16));
    }
    if (t + 2 < GNT) { stageA2(t + 2, 0); stageB4(t + 2); }
    asm volatile("s_barrier" ::: "memory");
    asm volatile("s_waitcnt lgkmcnt(0)" ::: "memory");
    __builtin_amdgcn_sched_barrier(0);
    __builtin_amdgcn_s_setprio(1);
#pragma unroll
    for (int mi = 0; mi < 4; ++mi)
#pragma unroll
      for (int ni = 0; ni < 4; ++ni)
#pragma unroll
        for (int kk = 0; kk < 2; ++kk)
          acc[4 + mi][ni] = __builtin_amdgcn_mfma_f32_16x16x32_bf16(bB[ni][kk], bA[mi][kk], acc[4 + mi][ni], 0, 0, 0);
    __builtin_amdgcn_s_setprio(0);
    if (t + 2 < GNT)       asm volatile("s_waitcnt vmcnt(8)" ::: "memory");
    else if (t + 2 == GNT) asm volatile("s_waitcnt vmcnt(2)" ::: "memory");
    asm volatile("s_barrier" ::: "memory");
  }

  // ---- epilogue: coalesced f32x4 normal stores ----
#pragma unroll
  for (int mf = 0; mf < 8; ++mf) {
    int row = m0 + wm * 128 + mf * 16 + l16;
    float* outp = Cout + (size_t)row * N + n0 + wn * 64;
#pragma unroll
    for (int ni = 0; ni < 4; ++ni) {
      f32x4 v = acc[mf][ni];
      f32x4 bv = *(const f32x4*)&bias[n0 + wn * 64 + ni * 16 + g * 4];
      v += bv;
      *(f32x4*)(outp + ni * 16 + g * 4) = v;
    }
  }
}

// ------------- MFMA flash attention: 128-row Q blocks, 8 waves, KVBLK=64 -------------
// Per (b,h): 16 blocks (vs 32) -> total KV stage+barrier units drop 528->288 (-45%).
// Per-wave code identical to the 64-row version; causal mask is exact per-element
// global comparison (kg > qg), with a per-wave fast-skip. Fully-masked tail tiles
// for low waves are inert (corr=1, ps=0). LDS 48 KB.
__global__ __launch_bounds__(512) void attn_mfma(
    const unsigned short* __restrict__ qkv, const unsigned short* __restrict__ vt,
    unsigned short* __restrict__ y) {
  __shared__ unsigned short Kl[2][4096];
  __shared__ unsigned short Vl[2][4096];
  __shared__ char Pl[16384];

  int bh = blockIdx.y;
  int b = bh >> 4, h = bh & 15;
  int qb = (T_SEQ / 128 - 1) - blockIdx.x;   // big Q-blocks first
  int tid = threadIdx.x;
  int lane = tid & 63, w = tid >> 6;         // w 0..7
  int l16 = lane & 15, g = lane >> 4;
  size_t bT = (size_t)b * T_SEQ;
  const float scale2 = 0.03125f * 1.44269504f;  // C^-0.5 * log2(e)

  int wrow0 = qb * 128 + w * 16;             // this wave's first q row (global)
  const unsigned short* qrow = qkv + (bT + wrow0 + l16) * 3072 + h * 64;
  bf16x8 qf[2] = { *(const bf16x8*)(qrow + g * 8), *(const bf16x8*)(qrow + 32 + g * 8) };

  f32x4 yacc[4] = {};
  float mrun[4], lrun[4];
#pragma unroll
  for (int j = 0; j < 4; ++j) { mrun[j] = -3.0e38f; lrun[j] = 0.f; }

  // 512 threads: 1 gload_lds per thread per operand per tile
  auto stageK = [&](int kb, int buf) {
    int row = tid >> 3, cpos = tid & 7;
    int c = cpos ^ (row & 7);
    const unsigned short* src = qkv + (bT + kb * 64 + row) * 3072 + 1024 + h * 64 + c * 8;
    __builtin_amdgcn_global_load_lds(
        (const __attribute__((address_space(1))) void*)src,
        (__attribute__((address_space(3))) void*)&Kl[buf][tid * 8], 16, 0, 0);
  };
  auto stageV = [&](int kb, int buf) {
    int row = tid >> 3, cpos = tid & 7;   // row = d channel
    int c = cpos ^ (row & 7);
    const unsigned short* src = vt + ((size_t)bh * 64 + row) * T_SEQ + kb * 64 + c * 8;
    __builtin_amdgcn_global_load_lds(
        (const __attribute__((address_space(1))) void*)src,
        (__attribute__((address_space(3))) void*)&Vl[buf][tid * 8], 16, 0, 0);
  };

  int ntiles = 2 * qb + 2;                   // kv tiles 0 .. 2qb+1
  stageK(0, 0); stageV(0, 0);

  for (int kb = 0; kb < ntiles; ++kb) {
    int buf = kb & 1;
    if (kb + 1 < ntiles) {
      stageK(kb + 1, buf ^ 1); stageV(kb + 1, buf ^ 1);
      asm volatile("s_waitcnt vmcnt(2)" ::: "memory");   // tile kb landed
    } else {
      asm volatile("s_waitcnt vmcnt(0)" ::: "memory");
    }
    asm volatile("s_barrier" ::: "memory");

    // ---- S = Q K^T ----
    f32x4 s[4] = {};
#pragma unroll
    for (int kk = 0; kk < 2; ++kk)
#pragma unroll
      for (int n = 0; n < 4; ++n) {
        int krow = n * 16 + l16;
        bf16x8 fb = *(const bf16x8*)((const char*)Kl[buf] + krow * 128 + (((kk * 4 + g) ^ (krow & 7)) * 16));
        s[n] = __builtin_amdgcn_mfma_f32_16x16x32_bf16(qf[kk], fb, s[n], 0, 0, 0);
      }

    // ---- online softmax (log2 domain), exact global causal mask ----
    bool diag = (kb * 64 + 63) > wrow0;      // any of this wave's rows maskable
    float pr[4][4];
    float corr[4];
#pragma unroll
    for (int j = 0; j < 4; ++j) {
      int qg = wrow0 + g * 4 + j;            // global q row
      float m = -3.0e38f;
#pragma unroll
      for (int n = 0; n < 4; ++n) {
        float v = s[n][j] * scale2;
        if (diag && (kb * 64 + n * 16 + l16) > qg) v = -3.0e38f;
        pr[n][j] = v;
        m = fmaxf(m, v);
      }
      m = fmaxf(m, __shfl_xor(m, 1));
      m = fmaxf(m, __shfl_xor(m, 2));
      m = fmaxf(m, __shfl_xor(m, 4));
      m = fmaxf(m, __shfl_xor(m, 8));
      float mn = fmaxf(mrun[j], m);
      corr[j] = exp2f(mrun[j] - mn);
      mrun[j] = mn;
      float ps = 0.f;
#pragma unroll
      for (int n = 0; n < 4; ++n) {
        float e = exp2f(pr[n][j] - mn);
        pr[n][j] = e;
        ps += e;
      }
      ps += __shfl_xor(ps, 1);
      ps += __shfl_xor(ps, 2);
      ps += __shfl_xor(ps, 4);
      ps += __shfl_xor(ps, 8);
      lrun[j] = lrun[j] * corr[j] + ps;
    }
#pragma unroll
    for (int n = 0; n < 4; ++n)
#pragma unroll
      for (int j = 0; j < 4; ++j)
        yacc[n][j] *= corr[j];

    // ---- P strip (wave-private rows w*16 .. w*16+15 of 128) ----
#pragma unroll
    for (int j = 0; j < 4; ++j) {
      int row = w * 16 + g * 4 + j;
#pragma unroll
      for (int n = 0; n < 4; ++n)
        *(unsigned short*)(Pl + ((row * 128 + (n * 16 + l16) * 2) ^ ((row & 7) << 4))) = f2bf(pr[n][j]);
    }

    // ---- y += P V ----
#pragma unroll
    for (int kk = 0; kk < 2; ++kk) {
      int prow = w * 16 + l16;
      bf16x8 fa = *(const bf16x8*)(Pl + ((prow * 128 + (kk * 32 + g * 8) * 2) ^ ((prow & 7) << 4)));
#pragma unroll
      for (int n = 0; n < 4; ++n) {
        int vrow = n * 16 + l16;
        bf16x8 fbv = *(const bf16x8*)((const char*)Vl[buf] + vrow * 128 + (((kk * 4 + g) ^ (vrow & 7)) * 16));
        yacc[n] = __builtin_amdgcn_mfma_f32_16x16x32_bf16(fa, fbv, yacc[n], 0, 0, 0);
      }
    }
    asm volatile("s_barrier" ::: "memory");   // protect buf before next restage
  }

  // ---- output ----
#pragma unroll
  for (int j = 0; j < 4; ++j) {
    float inv = 1.0f / lrun[j];
    int row = wrow0 + g * 4 + j;
    unsigned short* yo = y + (bT + row) * C_DIM + h * 64;
#pragma unroll
    for (int n = 0; n < 4; ++n)
      yo[n * 16 + l16] = f2bf(yacc[n][j] * inv);
  }
}

extern "C" void kernel_launch(void* const* d_in, const int* in_sizes, int n_in,
                              void* d_out, int out_size, void* d_ws, size_t ws_size,
                              hipStream_t stream) {
  const int*   x    = (const int*)d_in[0];
  const float* tok  = (const float*)d_in[1];
  const float* pos  = (const float*)d_in[2];
  const float* wq   = (const float*)d_in[3];
  const float* bq   = (const float*)d_in[4];
  const float* wk   = (const float*)d_in[5];
  const float* bk   = (const float*)d_in[6];
  const float* wv   = (const float*)d_in[7];
  const float* bv   = (const float*)d_in[8];
  const float* wh   = (const float*)d_in[9];
  const float* bhd  = (const float*)d_in[10];
  float* out = (float*)d_out;

  char* ws = (char*)d_ws;
  size_t off = 0;
  auto alloc = [&](size_t bytes) {
    void* p = ws + off;
    off += (bytes + 255) & ~(size_t)255;
    return p;
  };
  unsigned short* h_bf    = (unsigned short*)alloc((size_t)4096 * 1024 * 2);
  unsigned short* wqkv_t  = (unsigned short*)alloc((size_t)3072 * 1024 * 2);
  float*          qbias   = (float*)alloc((size_t)3072 * 4);
  unsigned short* wh_t    = (unsigned short*)alloc((size_t)V_DIM * 1024 * 2);
  unsigned short* qkv_bf  = (unsigned short*)alloc((size_t)4096 * 3072 * 2);
  unsigned short* vtb     = (unsigned short*)alloc((size_t)32 * 64 * T_SEQ * 2);
  unsigned short* ybf     = (unsigned short*)alloc((size_t)4096 * 1024 * 2);

  embed_kernel<<<4096, 256, 0, stream>>>(x, tok, pos, h_bf);
  repack_qkv<<<dim3(4096, 3), 256, 0, stream>>>(wq, wk, wv, bq, bk, bv, wqkv_t, qbias);
  repack_whead<<<dim3(V_DIM / 64, 16), 256, 0, stream>>>(wh, wh_t);
  // QKV proj (bf16 out, V written transposed to vtb): 768 blocks
  gemm_bf16_o16<<<768, 256, 0, stream>>>(h_bf, wqkv_t, qbias, qkv_bf, vtb, 3072, 32);
  // attention: 128-row Q blocks, 8 waves
  attn_mfma<<<dim3(T_SEQ / 128, 2 * H_N), 512, 0, stream>>>(qkv_bf, vtb, ybf);
  // head: M=4096, N=32000 -> 2000 blocks, identity order (L3 co-streaming)
  gemm256<<<2000, 512, 0, stream>>>(ybf, wh_t, bhd, out, V_DIM, 16);
}

// Round 17
// 559.837 us; speedup vs baseline: 1.0931x; 1.0091x over previous
//
#include <hip/hip_runtime.h>

#define T_SEQ 2048
#define C_DIM 1024
#define H_N   16
#define HS_D  64
#define V_DIM 32000

typedef float f32x4 __attribute__((ext_vector_type(4)));
typedef __bf16 bf16x8 __attribute__((ext_vector_type(8)));
typedef unsigned short us4 __attribute__((ext_vector_type(4)));
typedef unsigned short us8 __attribute__((ext_vector_type(8)));

__device__ inline unsigned short f2bf(float f) {
  unsigned int u = __float_as_uint(f);
  u = (u + 0x7FFFu + ((u >> 16) & 1u)) >> 16;
  return (unsigned short)u;
}

// ---------------- embed: h = tok_emb[x] + pos_emb, cast to bf16 ----------------
__global__ __launch_bounds__(256) void embed_kernel(
    const int* __restrict__ x, const float* __restrict__ tok,
    const float* __restrict__ pos, unsigned short* __restrict__ h) {
  int idx = blockIdx.x * 256 + threadIdx.x;   // over (B*T*C)/4
  int bt = idx >> 8;                          // 256 float4 per row
  int c4 = (idx & 255) * 4;
  int t = bt & (T_SEQ - 1);
  int tokid = x[bt];
  f32x4 a = *(const f32x4*)(tok + (size_t)tokid * C_DIM + c4);
  f32x4 b = *(const f32x4*)(pos + (size_t)t * C_DIM + c4);
  f32x4 s = a + b;
  us4 o;
  o[0] = f2bf(s[0]); o[1] = f2bf(s[1]); o[2] = f2bf(s[2]); o[3] = f2bf(s[3]);
  *(us4*)(h + (size_t)bt * C_DIM + c4) = o;
}

// ------------- repack wq/wk/wv [H,C,HS] f32 -> bf16 [3072][1024] (N,K) -------------
__global__ __launch_bounds__(256) void repack_qkv(
    const float* __restrict__ wq, const float* __restrict__ wk, const float* __restrict__ wv,
    const float* __restrict__ bq, const float* __restrict__ bk, const float* __restrict__ bv,
    unsigned short* __restrict__ wt, float* __restrict__ biasp) {
  int which = blockIdx.y;
  const float* w = (which == 0) ? wq : (which == 1) ? wk : wv;
  int i = blockIdx.x * 256 + threadIdx.x;   // 0 .. H*C*HS (=1M)
  int d = i & 63;
  int c = (i >> 6) & (C_DIM - 1);
  int hh = i >> 16;
  int n = which * 1024 + hh * 64 + d;
  wt[(size_t)n * C_DIM + c] = f2bf(w[i]);
  if (c == 0) {
    const float* bb = (which == 0) ? bq : (which == 1) ? bk : bv;
    biasp[n] = bb[hh * 64 + d];
  }
}

// ------------- transpose-repack w_head [C,V] f32 -> bf16 [V][C], vectorized -------------
__global__ __launch_bounds__(256) void repack_whead(
    const float* __restrict__ wh, unsigned short* __restrict__ wht) {
  __shared__ float tile[64][65];
  int v0 = blockIdx.x * 64;
  int c0 = blockIdx.y * 64;
  int tr = threadIdx.x >> 4;         // 0..15
  int tc = (threadIdx.x & 15) * 4;   // 0,4,..,60
#pragma unroll
  for (int i = 0; i < 4; ++i) {
    int r = i * 16 + tr;             // c-row
    *(f32x4*)&tile[r][tc] = *(const f32x4*)&wh[(size_t)(c0 + r) * V_DIM + v0 + tc];
  }
  __syncthreads();
#pragma unroll
  for (int i = 0; i < 4; ++i) {
    int vr = i * 16 + tr;            // v-row
    us4 o;
#pragma unroll
    for (int k = 0; k < 4; ++k) o[k] = f2bf(tile[tc + k][vr]);
    *(us4*)&wht[(size_t)(v0 + vr) * C_DIM + c0 + tc] = o;
  }
}

// ------------- 128x128 4-wave QKV GEMM, bf16 out, V-transpose fused -------------
__global__ __launch_bounds__(256) void gemm_bf16_o16(
    const unsigned short* __restrict__ A, const unsigned short* __restrict__ Bt,
    const float* __restrict__ bias, unsigned short* __restrict__ Cout,
    unsigned short* __restrict__ vt, int N, int Mtiles) {
  const int K = 1024;
  __shared__ unsigned short As[128 * 32];
  __shared__ unsigned short Bs[128 * 32];
  int tid = threadIdx.x;
  int lane = tid & 63, wvi = tid >> 6;
  int cpx = gridDim.x >> 3;
  int lin = blockIdx.x;
  int wg = (lin & 7) * cpx + (lin >> 3);
  int m0 = (wg % Mtiles) * 128;
  int n0 = (wg / Mtiles) * 128;
  int wmm = (wvi >> 1) * 64, wnn = (wvi & 1) * 64;
  int r16 = lane & 15, gg = lane >> 4;
  f32x4 acc[4][4] = {};

  for (int k0 = 0; k0 < K; k0 += 32) {
#pragma unroll
    for (int it = 0; it < 2; ++it) {
      int ch = it * 256 + wvi * 64 + lane;
      int row = ch >> 2, cc = (ch & 3) * 8;
      const unsigned short* ga = A + (size_t)(m0 + row) * K + k0 + cc;
      __builtin_amdgcn_global_load_lds(
          (const __attribute__((address_space(1))) void*)ga,
          (__attribute__((address_space(3))) void*)&As[ch * 8], 16, 0, 0);
      const unsigned short* gb = Bt + (size_t)(n0 + row) * K + k0 + cc;
      __builtin_amdgcn_global_load_lds(
          (const __attribute__((address_space(1))) void*)gb,
          (__attribute__((address_space(3))) void*)&Bs[ch * 8], 16, 0, 0);
    }
    __syncthreads();
    bf16x8 fa[4], fb[4];
#pragma unroll
    for (int m = 0; m < 4; ++m)
      fa[m] = *(const bf16x8*)&As[(wmm + m * 16 + r16) * 32 + gg * 8];
#pragma unroll
    for (int n = 0; n < 4; ++n)
      fb[n] = *(const bf16x8*)&Bs[(wnn + n * 16 + r16) * 32 + gg * 8];
#pragma unroll
    for (int m = 0; m < 4; ++m)
#pragma unroll
      for (int n = 0; n < 4; ++n)
        acc[m][n] = __builtin_amdgcn_mfma_f32_16x16x32_bf16(fa[m], fb[n], acc[m][n], 0, 0, 0);
    __syncthreads();
  }
#pragma unroll
  for (int m = 0; m < 4; ++m) {
    int row = m0 + wmm + m * 16 + gg * 4;
#pragma unroll
    for (int n = 0; n < 4; ++n) {
      int col = n0 + wnn + n * 16 + r16;
      float bval = bias[col];
      if (n0 < 2048) {   // Q/K tile (uniform branch; n0 multiple of 128)
#pragma unroll
        for (int j = 0; j < 4; ++j)
          Cout[(size_t)(row + j) * N + col] = f2bf(acc[m][n][j] + bval);
      } else {           // V tile -> transposed vt[b*16+h][d][t]
        int d = (col - 2048) & 63, hh = (col - 2048) >> 6;
        int b = row >> 11, t0 = row & 2047;
        us4 o;
#pragma unroll
        for (int j = 0; j < 4; ++j) o[j] = f2bf(acc[m][n][j] + bval);
        *(us4*)&vt[((size_t)(b * 16 + hh) * 64 + d) * T_SEQ + t0] = o;
      }
    }
  }
}

// ------------- head GEMM: 128x256 tile, 8 waves, single-buf LDS, 2 blocks/CU -------------
// Unified-VGPR occupancy plan: per-wave 64x64 output -> acc 64 regs; kk-split frags
// (32 live); __launch_bounds__(512,4) caps at 128 regs -> 4 waves/SIMD -> TWO
// co-resident blocks (LDS 48 KB single-buffered). Cross-block overlap hides the
// per-block C-write epilogue (~10.6 us) and staging drains that were serial at
// 1 block/CU (R16: 44 us/block vs 14 us MFMA floor).
// Per K-tile: reads kk0 -> 16 MFMA -> reads kk1 -> lgkmcnt(0) -> barrier(release)
// -> stage(t+1) -> 16 MFMA (overlaps staging) -> vmcnt(0) -> barrier.
// Identity block order, m-fastest (R15: L3 co-streaming of the shared B panel).
// Swizzle = verified zero-conflict (128-B rows, src col c=cpos^(row&7)).
#define GK 1024
#define GNT 16   // K / 64

__global__ __launch_bounds__(512, 4) void gemm_head(
    const unsigned short* __restrict__ A, const unsigned short* __restrict__ Bt,
    const float* __restrict__ bias, float* __restrict__ Cout, int N, int Mtiles) {
  __shared__ unsigned short As[128 * 64];   // 16 KB
  __shared__ unsigned short Bs[256 * 64];   // 32 KB
  int tid = threadIdx.x;
  int lane = tid & 63;
  int wid = tid >> 6;
  int wm = wid >> 2, wn = wid & 3;          // 2M x 4N waves, per-wave 64x64
  int l16 = lane & 15, g = lane >> 4;

  int wg = blockIdx.x;                      // identity order
  int m0 = (wg % Mtiles) * 128;
  int n0 = (wg / Mtiles) * 256;

  auto stageA = [&](int kt) {
#pragma unroll
    for (int q = 0; q < 2; ++q) {
      int chunk = q * 512 + tid;            // 0..1023
      int row = chunk >> 3, cpos = chunk & 7;
      int c = cpos ^ (row & 7);
      const unsigned short* src = A + (size_t)(m0 + row) * GK + kt * 64 + c * 8;
      __builtin_amdgcn_global_load_lds(
          (const __attribute__((address_space(1))) void*)src,
          (__attribute__((address_space(3))) void*)(As + row * 64 + cpos * 8), 16, 0, 0);
    }
  };
  auto stageB = [&](int kt) {
#pragma unroll
    for (int q = 0; q < 4; ++q) {
      int chunk = q * 512 + tid;            // 0..2047
      int row = chunk >> 3, cpos = chunk & 7;
      int c = cpos ^ (row & 7);
      const unsigned short* src = Bt + (size_t)(n0 + row) * GK + kt * 64 + c * 8;
      __builtin_amdgcn_global_load_lds(
          (const __attribute__((address_space(1))) void*)src,
          (__attribute__((address_space(3))) void*)(Bs + row * 64 + cpos * 8), 16, 0, 0);
    }
  };

  stageA(0); stageB(0);
  asm volatile("s_waitcnt vmcnt(0)" ::: "memory");
  asm volatile("s_barrier" ::: "memory");

  f32x4 acc[4][4] = {};

  for (int t = 0; t < GNT; ++t) {
    bf16x8 bA[4], bB[4];
    // ---- kk = 0 ----
#pragma unroll
    for (int mi = 0; mi < 4; ++mi) {
      int row = wm * 64 + mi * 16 + l16;
      bA[mi] = *(const bf16x8*)((const char*)As + row * 128 + ((g ^ (row & 7)) * 16));
    }
#pragma unroll
    for (int ni = 0; ni < 4; ++ni) {
      int row = wn * 64 + ni * 16 + l16;
      bB[ni] = *(const bf16x8*)((const char*)Bs + row * 128 + ((g ^ (row & 7)) * 16));
    }
#pragma unroll
    for (int mi = 0; mi < 4; ++mi)
#pragma unroll
      for (int ni = 0; ni < 4; ++ni)
        acc[mi][ni] = __builtin_amdgcn_mfma_f32_16x16x32_bf16(bB[ni], bA[mi], acc[mi][ni], 0, 0, 0);
    // ---- kk = 1 reads ----
#pragma unroll
    for (int mi = 0; mi < 4; ++mi) {
      int row = wm * 64 + mi * 16 + l16;
      bA[mi] = *(const bf16x8*)((const char*)As + row * 128 + (((4 + g) ^ (row & 7)) * 16));
    }
#pragma unroll
    for (int ni = 0; ni < 4; ++ni) {
      int row = wn * 64 + ni * 16 + l16;
      bB[ni] = *(const bf16x8*)((const char*)Bs + row * 128 + (((4 + g) ^ (row & 7)) * 16));
    }
    asm volatile("s_waitcnt lgkmcnt(0)" ::: "memory");
    __builtin_amdgcn_sched_barrier(0);
    asm volatile("s_barrier" ::: "memory");   // all reads of tile t done -> buffer free
    if (t + 1 < GNT) { stageA(t + 1); stageB(t + 1); }
    __builtin_amdgcn_s_setprio(1);
#pragma unroll
    for (int mi = 0; mi < 4; ++mi)
#pragma unroll
      for (int ni = 0; ni < 4; ++ni)
        acc[mi][ni] = __builtin_amdgcn_mfma_f32_16x16x32_bf16(bB[ni], bA[mi], acc[mi][ni], 0, 0, 0);
    __builtin_amdgcn_s_setprio(0);
    if (t + 1 < GNT) {
      asm volatile("s_waitcnt vmcnt(0)" ::: "memory");
      asm volatile("s_barrier" ::: "memory");
    }
  }

  // ---- epilogue: swapped layout -> coalesced f32x4 stores ----
#pragma unroll
  for (int mf = 0; mf < 4; ++mf) {
    int row = m0 + wm * 64 + mf * 16 + l16;
    float* outp = Cout + (size_t)row * N + n0 + wn * 64;
#pragma unroll
    for (int ni = 0; ni < 4; ++ni) {
      f32x4 v = acc[mf][ni];
      f32x4 bv = *(const f32x4*)&bias[n0 + wn * 64 + ni * 16 + g * 4];
      v += bv;
      *(f32x4*)(outp + ni * 16 + g * 4) = v;
    }
  }
}

// ------------- MFMA flash attention: 128-row Q blocks, 8 waves, KVBLK=64 -------------
__global__ __launch_bounds__(512) void attn_mfma(
    const unsigned short* __restrict__ qkv, const unsigned short* __restrict__ vt,
    unsigned short* __restrict__ y) {
  __shared__ unsigned short Kl[2][4096];
  __shared__ unsigned short Vl[2][4096];
  __shared__ char Pl[16384];

  int bh = blockIdx.y;
  int b = bh >> 4, h = bh & 15;
  int qb = (T_SEQ / 128 - 1) - blockIdx.x;   // big Q-blocks first
  int tid = threadIdx.x;
  int lane = tid & 63, w = tid >> 6;         // w 0..7
  int l16 = lane & 15, g = lane >> 4;
  size_t bT = (size_t)b * T_SEQ;
  const float scale2 = 0.03125f * 1.44269504f;  // C^-0.5 * log2(e)

  int wrow0 = qb * 128 + w * 16;             // this wave's first q row (global)
  const unsigned short* qrow = qkv + (bT + wrow0 + l16) * 3072 + h * 64;
  bf16x8 qf[2] = { *(const bf16x8*)(qrow + g * 8), *(const bf16x8*)(qrow + 32 + g * 8) };

  f32x4 yacc[4] = {};
  float mrun[4], lrun[4];
#pragma unroll
  for (int j = 0; j < 4; ++j) { mrun[j] = -3.0e38f; lrun[j] = 0.f; }

  auto stageK = [&](int kb, int buf) {
    int row = tid >> 3, cpos = tid & 7;
    int c = cpos ^ (row & 7);
    const unsigned short* src = qkv + (bT + kb * 64 + row) * 3072 + 1024 + h * 64 + c * 8;
    __builtin_amdgcn_global_load_lds(
        (const __attribute__((address_space(1))) void*)src,
        (__attribute__((address_space(3))) void*)&Kl[buf][tid * 8], 16, 0, 0);
  };
  auto stageV = [&](int kb, int buf) {
    int row = tid >> 3, cpos = tid & 7;   // row = d channel
    int c = cpos ^ (row & 7);
    const unsigned short* src = vt + ((size_t)bh * 64 + row) * T_SEQ + kb * 64 + c * 8;
    __builtin_amdgcn_global_load_lds(
        (const __attribute__((address_space(1))) void*)src,
        (__attribute__((address_space(3))) void*)&Vl[buf][tid * 8], 16, 0, 0);
  };

  int ntiles = 2 * qb + 2;                   // kv tiles 0 .. 2qb+1
  stageK(0, 0); stageV(0, 0);

  for (int kb = 0; kb < ntiles; ++kb) {
    int buf = kb & 1;
    if (kb + 1 < ntiles) {
      stageK(kb + 1, buf ^ 1); stageV(kb + 1, buf ^ 1);
      asm volatile("s_waitcnt vmcnt(2)" ::: "memory");   // tile kb landed
    } else {
      asm volatile("s_waitcnt vmcnt(0)" ::: "memory");
    }
    asm volatile("s_barrier" ::: "memory");

    // ---- S = Q K^T ----
    f32x4 s[4] = {};
#pragma unroll
    for (int kk = 0; kk < 2; ++kk)
#pragma unroll
      for (int n = 0; n < 4; ++n) {
        int krow = n * 16 + l16;
        bf16x8 fb = *(const bf16x8*)((const char*)Kl[buf] + krow * 128 + (((kk * 4 + g) ^ (krow & 7)) * 16));
        s[n] = __builtin_amdgcn_mfma_f32_16x16x32_bf16(qf[kk], fb, s[n], 0, 0, 0);
      }

    // ---- online softmax (log2 domain), exact global causal mask ----
    bool diag = (kb * 64 + 63) > wrow0;      // any of this wave's rows maskable
    float pr[4][4];
    float corr[4];
#pragma unroll
    for (int j = 0; j < 4; ++j) {
      int qg = wrow0 + g * 4 + j;            // global q row
      float m = -3.0e38f;
#pragma unroll
      for (int n = 0; n < 4; ++n) {
        float v = s[n][j] * scale2;
        if (diag && (kb * 64 + n * 16 + l16) > qg) v = -3.0e38f;
        pr[n][j] = v;
        m = fmaxf(m, v);
      }
      m = fmaxf(m, __shfl_xor(m, 1));
      m = fmaxf(m, __shfl_xor(m, 2));
      m = fmaxf(m, __shfl_xor(m, 4));
      m = fmaxf(m, __shfl_xor(m, 8));
      float mn = fmaxf(mrun[j], m);
      corr[j] = exp2f(mrun[j] - mn);
      mrun[j] = mn;
      float ps = 0.f;
#pragma unroll
      for (int n = 0; n < 4; ++n) {
        float e = exp2f(pr[n][j] - mn);
        pr[n][j] = e;
        ps += e;
      }
      ps += __shfl_xor(ps, 1);
      ps += __shfl_xor(ps, 2);
      ps += __shfl_xor(ps, 4);
      ps += __shfl_xor(ps, 8);
      lrun[j] = lrun[j] * corr[j] + ps;
    }
#pragma unroll
    for (int n = 0; n < 4; ++n)
#pragma unroll
      for (int j = 0; j < 4; ++j)
        yacc[n][j] *= corr[j];

    // ---- P strip (wave-private rows w*16 .. w*16+15 of 128) ----
#pragma unroll
    for (int j = 0; j < 4; ++j) {
      int row = w * 16 + g * 4 + j;
#pragma unroll
      for (int n = 0; n < 4; ++n)
        *(unsigned short*)(Pl + ((row * 128 + (n * 16 + l16) * 2) ^ ((row & 7) << 4))) = f2bf(pr[n][j]);
    }

    // ---- y += P V ----
#pragma unroll
    for (int kk = 0; kk < 2; ++kk) {
      int prow = w * 16 + l16;
      bf16x8 fa = *(const bf16x8*)(Pl + ((prow * 128 + (kk * 32 + g * 8) * 2) ^ ((prow & 7) << 4)));
#pragma unroll
      for (int n = 0; n < 4; ++n) {
        int vrow = n * 16 + l16;
        bf16x8 fbv = *(const bf16x8*)((const char*)Vl[buf] + vrow * 128 + (((kk * 4 + g) ^ (vrow & 7)) * 16));
        yacc[n] = __builtin_amdgcn_mfma_f32_16x16x32_bf16(fa, fbv, yacc[n], 0, 0, 0);
      }
    }
    asm volatile("s_barrier" ::: "memory");   // protect buf before next restage
  }

  // ---- output ----
#pragma unroll
  for (int j = 0; j < 4; ++j) {
    float inv = 1.0f / lrun[j];
    int row = wrow0 + g * 4 + j;
    unsigned short* yo = y + (bT + row) * C_DIM + h * 64;
#pragma unroll
    for (int n = 0; n < 4; ++n)
      yo[n * 16 + l16] = f2bf(yacc[n][j] * inv);
  }
}

extern "C" void kernel_launch(void* const* d_in, const int* in_sizes, int n_in,
                              void* d_out, int out_size, void* d_ws, size_t ws_size,
                              hipStream_t stream) {
  const int*   x    = (const int*)d_in[0];
  const float* tok  = (const float*)d_in[1];
  const float* pos  = (const float*)d_in[2];
  const float* wq   = (const float*)d_in[3];
  const float* bq   = (const float*)d_in[4];
  const float* wk   = (const float*)d_in[5];
  const float* bk   = (const float*)d_in[6];
  const float* wv   = (const float*)d_in[7];
  const float* bv   = (const float*)d_in[8];
  const float* wh   = (const float*)d_in[9];
  const float* bhd  = (const float*)d_in[10];
  float* out = (float*)d_out;

  char* ws = (char*)d_ws;
  size_t off = 0;
  auto alloc = [&](size_t bytes) {
    void* p = ws + off;
    off += (bytes + 255) & ~(size_t)255;
    return p;
  };
  unsigned short* h_bf    = (unsigned short*)alloc((size_t)4096 * 1024 * 2);
  unsigned short* wqkv_t  = (unsigned short*)alloc((size_t)3072 * 1024 * 2);
  float*          qbias   = (float*)alloc((size_t)3072 * 4);
  unsigned short* wh_t    = (unsigned short*)alloc((size_t)V_DIM * 1024 * 2);
  unsigned short* qkv_bf  = (unsigned short*)alloc((size_t)4096 * 3072 * 2);
  unsigned short* vtb     = (unsigned short*)alloc((size_t)32 * 64 * T_SEQ * 2);
  unsigned short* ybf     = (unsigned short*)alloc((size_t)4096 * 1024 * 2);

  embed_kernel<<<4096, 256, 0, stream>>>(x, tok, pos, h_bf);
  repack_qkv<<<dim3(4096, 3), 256, 0, stream>>>(wq, wk, wv, bq, bk, bv, wqkv_t, qbias);
  repack_whead<<<dim3(V_DIM / 64, 16), 256, 0, stream>>>(wh, wh_t);
  // QKV proj (bf16 out, V written transposed to vtb): 768 blocks
  gemm_bf16_o16<<<768, 256, 0, stream>>>(h_bf, wqkv_t, qbias, qkv_bf, vtb, 3072, 32);
  // attention: 128-row Q blocks, 8 waves
  attn_mfma<<<dim3(T_SEQ / 128, 2 * H_N), 512, 0, stream>>>(qkv_bf, vtb, ybf);
  // head: 128x256 tiles -> 32 x 125 = 4000 blocks, identity order, 2 blocks/CU
  gemm_head<<<4000, 512, 0, stream>>>(ybf, wh_t, bhd, out, V_DIM, 32);
}